// Round 6
// baseline (462.301 us; speedup 1.0000x reference)
//
#include <hip/hip_runtime.h>

// CausalAttention: B=4, S=4096, D=1024 (single head, head_dim=1024)
// v6: cast -> QKV GEMM (VT) -> S-GEMM+exp (packed causal triangle, bf16)
//     -> l-reduce -> PV GEMM (scale 1/l). No-max softmax (validated R1).
// R6: all GEMMs use a 4-slot k32-sub-tile pipeline with counted vmcnt
// (T3+T4) + setprio (T5): per phase {stage(s+3) -> slot (s-1)&3; vmcnt(12);
// s_barrier; 12 ds_read + 32 MFMA; lgkmcnt(0); s_barrier}. Loads never drain
// to 0 in steady state (3 sub-tiles in flight). LDS bijection
// p(r,c)=(r>>4)*64+(r&15)*4+(c^(r&3)) keeps gld_lds lane-linear and frag
// reads conflict-free (64 distinct 16B slots per wave read).
// ws (u16 elems): Wqkv[3M] | X[16M, reused as zero-tile] | Q[16M] | K[16M] |
//   VT[16M] | Spack[34.6M packed 128-tiles] | lpart | linv

typedef unsigned short u16;
typedef unsigned int u32;
typedef __attribute__((ext_vector_type(8))) short bf16x8;
typedef __attribute__((ext_vector_type(4))) float f32x4;
typedef __attribute__((ext_vector_type(8))) unsigned short u16x8;

__device__ __forceinline__ u16 f2bf(float f) {
  union { float f; unsigned u; } v; v.f = f;
  unsigned r = v.u + 0x7FFFu + ((v.u >> 16) & 1u);  // RNE
  return (u16)(r >> 16);
}
__device__ __forceinline__ float bf2f(u16 h) {
  union { unsigned u; float f; } v; v.u = ((unsigned)h) << 16;
  return v.f;
}
__device__ __forceinline__ f32x4 mfma16(bf16x8 a, bf16x8 b, f32x4 c) {
  return __builtin_amdgcn_mfma_f32_16x16x32_bf16(a, b, c, 0, 0, 0);
}
__device__ __forceinline__ void gld_lds16(const u16* g, u16* l) {
  __builtin_amdgcn_global_load_lds(
      (const __attribute__((address_space(1))) u32*)g,
      (__attribute__((address_space(3))) u32*)l, 16, 0, 0);
}

// ---------------- cast f32 -> bf16, 8 elems/thread ----------------
__global__ __launch_bounds__(256)
void cast_f32_bf16(const float* __restrict__ src, u16* __restrict__ dst, int n8) {
  int i = blockIdx.x * 256 + threadIdx.x;
  if (i >= n8) return;
  const float4* s4 = (const float4*)src;
  float4 a = s4[2*i], b = s4[2*i+1];
  u16x8 o;
  o[0]=f2bf(a.x); o[1]=f2bf(a.y); o[2]=f2bf(a.z); o[3]=f2bf(a.w);
  o[4]=f2bf(b.x); o[5]=f2bf(b.y); o[6]=f2bf(b.z); o[7]=f2bf(b.w);
  ((u16x8*)dst)[i] = o;
}

// ---------------- fused QKV GEMM: 256x256, 4-slot k32 pipeline ----------------
__global__ __launch_bounds__(512)
void qkv_gemm(const u16* __restrict__ X, const u16* __restrict__ W,
              u16* __restrict__ Qo, u16* __restrict__ Ko, u16* __restrict__ VTo) {
  __shared__ __align__(16) u16 LA[4][8192];   // 4 slots x (256 rows x 32 k)
  __shared__ __align__(16) u16 LB[4][8192];
  const int tid = threadIdx.x;
  const int w = tid >> 6, lane = tid & 63;
  const int g = lane >> 4, c16 = lane & 15;
  const int wr = w >> 2, wc = w & 3;           // wave out: rows wr*128, cols wc*64
  const int M0 = blockIdx.x * 256;
  const int N0 = blockIdx.y * 256;

  f32x4 acc[8][4] = {};
  const int roff = c16 * 32 + ((g ^ (c16 & 3)) * 8);   // lane read offset in 512-elem group

  auto stage = [&](int s) {
    const int slot = s & 3;
    const int k0 = s * 32;
#pragma unroll
    for (int i = 0; i < 2; ++i) {
      int p = i * 512 + tid;                   // lane-linear LDS position
      int r = ((p >> 6) << 4) | ((p >> 2) & 15);
      int c = (p & 3) ^ ((p >> 2) & 3);        // inverse-swizzled global chunk
      gld_lds16(X + (size_t)(M0 + r) * 1024 + k0 + c * 8, &LA[slot][p * 8]);
    }
#pragma unroll
    for (int i = 0; i < 2; ++i) {
      int p = i * 512 + tid;
      int r = ((p >> 6) << 4) | ((p >> 2) & 15);
      int c = (p & 3) ^ ((p >> 2) & 3);
      gld_lds16(W + (size_t)(N0 + r) * 1024 + k0 + c * 8, &LB[slot][p * 8]);
    }
  };

  stage(0); stage(1); stage(2);
  for (int s = 0; s < 32; ++s) {
    if (s + 3 < 32) {
      stage(s + 3);                            // -> slot (s-1)&3, freed by release(s-1)
      asm volatile("s_waitcnt vmcnt(12)" ::: "memory");   // sub s landed (3 stages x 4 newer)
    } else {
      asm volatile("s_waitcnt vmcnt(0)" ::: "memory");
    }
    __builtin_amdgcn_sched_barrier(0);
    __builtin_amdgcn_s_barrier();              // acquire
    __builtin_amdgcn_sched_barrier(0);
    {
      const int slot = s & 3;
      const u16* A = LA[slot];
      const u16* B = LB[slot];
      bf16x8 af[8], bf[4];
#pragma unroll
      for (int m = 0; m < 8; ++m)
        af[m] = *(const bf16x8*)&A[(wr * 8 + m) * 512 + roff];
#pragma unroll
      for (int n = 0; n < 4; ++n)
        bf[n] = *(const bf16x8*)&B[(wc * 4 + n) * 512 + roff];
      __builtin_amdgcn_s_setprio(1);
#pragma unroll
      for (int m = 0; m < 8; ++m)
#pragma unroll
        for (int n = 0; n < 4; ++n)
          acc[m][n] = mfma16(af[m], bf[n], acc[m][n]);
      __builtin_amdgcn_s_setprio(0);
    }
    asm volatile("s_waitcnt lgkmcnt(0)" ::: "memory");
    __builtin_amdgcn_sched_barrier(0);
    __builtin_amdgcn_s_barrier();              // release: slot s&3 reusable
    __builtin_amdgcn_sched_barrier(0);
  }

  const int which = N0 >> 10;                  // 0=Q, 1=K, 2=V
  const int colbase = N0 & 1023;
#pragma unroll
  for (int m = 0; m < 8; ++m) {
#pragma unroll
    for (int n = 0; n < 4; ++n) {
#pragma unroll
      for (int r = 0; r < 4; ++r) {
        int gm  = M0 + wr * 128 + m * 16 + 4 * g + r;
        int col = colbase + wc * 64 + n * 16 + c16;
        u16 hv = f2bf(acc[m][n][r]);
        if (which == 0) {
          Qo[(size_t)gm * 1024 + col] = hv;
        } else if (which == 1) {
          Ko[(size_t)gm * 1024 + col] = hv;
        } else {
          int b = gm >> 12, s2 = gm & 4095;
          VTo[((size_t)((b << 10) + col)) * 4096 + s2] = hv;
        }
      }
    }
  }
}

// ---------------- S-GEMM + exp: 256x256 causal tiles, 4-slot pipeline ----------------
__global__ __launch_bounds__(512)
void sgemm_exp(const u16* __restrict__ Q, const u16* __restrict__ K,
               u16* __restrict__ Spack, float* __restrict__ lpart) {
  __shared__ __align__(16) u16 LA[4][8192];
  __shared__ __align__(16) u16 LB[4][8192];
  __shared__ float lsum[256][4];
  const int tid = threadIdx.x;
  const int w = tid >> 6, lane = tid & 63;
  const int g = lane >> 4, c16 = lane & 15;
  const int wr = w >> 2, wc = w & 3;
  const int b = blockIdx.y;

  int L = blockIdx.x, qt = 0;                  // triangular decode
  while ((qt + 1) * (qt + 2) / 2 <= L) ++qt;
  const int kt = L - qt * (qt + 1) / 2;

  const u16* Qb = Q + (size_t)b * 4096 * 1024 + (size_t)qt * 256 * 1024;
  const u16* Kb = K + (size_t)b * 4096 * 1024 + (size_t)kt * 256 * 1024;

  f32x4 acc[8][4] = {};
  const int roff = c16 * 32 + ((g ^ (c16 & 3)) * 8);

  auto stage = [&](int s) {
    const int slot = s & 3;
    const int k0 = s * 32;
#pragma unroll
    for (int i = 0; i < 2; ++i) {
      int p = i * 512 + tid;
      int r = ((p >> 6) << 4) | ((p >> 2) & 15);
      int c = (p & 3) ^ ((p >> 2) & 3);
      gld_lds16(Qb + (size_t)r * 1024 + k0 + c * 8, &LA[slot][p * 8]);
    }
#pragma unroll
    for (int i = 0; i < 2; ++i) {
      int p = i * 512 + tid;
      int r = ((p >> 6) << 4) | ((p >> 2) & 15);
      int c = (p & 3) ^ ((p >> 2) & 3);
      gld_lds16(Kb + (size_t)r * 1024 + k0 + c * 8, &LB[slot][p * 8]);
    }
  };

  stage(0); stage(1); stage(2);
  for (int s = 0; s < 32; ++s) {
    if (s + 3 < 32) {
      stage(s + 3);
      asm volatile("s_waitcnt vmcnt(12)" ::: "memory");
    } else {
      asm volatile("s_waitcnt vmcnt(0)" ::: "memory");
    }
    __builtin_amdgcn_sched_barrier(0);
    __builtin_amdgcn_s_barrier();
    __builtin_amdgcn_sched_barrier(0);
    {
      const int slot = s & 3;
      const u16* A = LA[slot];
      const u16* B = LB[slot];
      bf16x8 af[8], bf[4];
#pragma unroll
      for (int m = 0; m < 8; ++m)
        af[m] = *(const bf16x8*)&A[(wr * 8 + m) * 512 + roff];
#pragma unroll
      for (int n = 0; n < 4; ++n)
        bf[n] = *(const bf16x8*)&B[(wc * 4 + n) * 512 + roff];
      __builtin_amdgcn_s_setprio(1);
#pragma unroll
      for (int m = 0; m < 8; ++m)
#pragma unroll
        for (int n = 0; n < 4; ++n)
          acc[m][n] = mfma16(af[m], bf[n], acc[m][n]);
      __builtin_amdgcn_s_setprio(0);
    }
    asm volatile("s_waitcnt lgkmcnt(0)" ::: "memory");
    __builtin_amdgcn_sched_barrier(0);
    __builtin_amdgcn_s_barrier();
    __builtin_amdgcn_sched_barrier(0);
  }

  // epilogue: exp + mask, store into 128-tile packed layout, row-sum partials.
  const int qt128 = 2 * qt + wr;
  const int kt128 = 2 * kt + (wc >> 1);
  const bool exists = (kt128 <= qt128);
  u16* Sb = Spack + (((size_t)b * 528 + (size_t)(qt128 * (qt128 + 1)) / 2 + kt128) << 14);
  const int q0 = qt * 256, k0g = kt * 256;
  float psum[8][4];
#pragma unroll
  for (int m = 0; m < 8; ++m)
#pragma unroll
    for (int r = 0; r < 4; ++r) psum[m][r] = 0.f;
#pragma unroll
  for (int m = 0; m < 8; ++m) {
#pragma unroll
    for (int n = 0; n < 4; ++n) {
#pragma unroll
      for (int r = 0; r < 4; ++r) {
        int rl = wr * 128 + m * 16 + 4 * g + r;
        int cl = wc * 64 + n * 16 + c16;
        float s = acc[m][n][r] * 0.03125f;     // 1/sqrt(1024)
        float p = (k0g + cl <= q0 + rl) ? __expf(s) : 0.f;
        u16 pb = f2bf(p);
        if (exists) Sb[(rl & 127) * 128 + (cl & 127)] = pb;
        psum[m][r] += bf2f(pb);
      }
    }
  }
#pragma unroll
  for (int m = 0; m < 8; ++m)
#pragma unroll
    for (int r = 0; r < 4; ++r) {
      float v = psum[m][r];
      v += __shfl_xor(v, 1, 64);
      v += __shfl_xor(v, 2, 64);
      v += __shfl_xor(v, 4, 64);
      v += __shfl_xor(v, 8, 64);
      psum[m][r] = v;
    }
  if (c16 == 0) {
#pragma unroll
    for (int m = 0; m < 8; ++m)
#pragma unroll
      for (int r = 0; r < 4; ++r)
        lsum[wr * 128 + m * 16 + 4 * g + r][wc] = psum[m][r];
  }
  __syncthreads();
  if (tid < 256) {
    float v = lsum[tid][0] + lsum[tid][1] + lsum[tid][2] + lsum[tid][3];
    lpart[((size_t)b * 4096 + q0 + tid) * 16 + kt] = v;
  }
}

// ---------------- l reduction -> 1/l ----------------
__global__ __launch_bounds__(256)
void lreduce(const float* __restrict__ lpart, float* __restrict__ linv) {
  int row = blockIdx.x * 256 + threadIdx.x;    // 0..16383
  int nt  = ((row & 4095) >> 8) + 1;           // valid 256-col partials
  const float* p = lpart + (size_t)row * 16;
  float s = 0.f;
  for (int i = 0; i < nt; ++i) s += p[i];
  linv[row] = 1.f / s;
}

// ---------------- PV GEMM: 256x128 paired q-tiles, 4-slot pipeline ----------------
__global__ __launch_bounds__(512)
void pv_gemm(const u16* __restrict__ Spack, const u16* __restrict__ VT,
             const u16* __restrict__ ztile, const float* __restrict__ linv,
             float* __restrict__ Out) {
  __shared__ __align__(16) u16 LA[4][8192];    // 256 x 32
  __shared__ __align__(16) u16 LB[4][4096];    // 128 x 32
  const int tid = threadIdx.x;
  const int w = tid >> 6, lane = tid & 63;
  const int g = lane >> 4, c16 = lane & 15;
  const int wm = w >> 1, wn = w & 1;           // wave out: rows wm*64, cols wn*64
  const int pp = blockIdx.x;
  const int d0 = blockIdx.y;
  const int b  = blockIdx.z;

  const u16* Sp_b = Spack + (size_t)b * 528 * 16384;
  const u16* VTb  = VT + (size_t)b * 1024 * 4096;
  float* Ob = Out + (size_t)b * 4096 * 1024;
  const int roff = c16 * 32 + ((g ^ (c16 & 3)) * 8);

  for (int pass = 0; pass < 2; ++pass) {
    const int QT = pass == 0 ? pp : 15 - pp;
    const int M0 = QT * 256;
    const int nsub = (QT + 1) * 8;             // k32 sub-tiles
    const int tLo = 2 * QT;
    const size_t triLo = (size_t)(tLo * (tLo + 1)) / 2;
    const size_t triHi = (size_t)((tLo + 1) * (tLo + 2)) / 2;

    f32x4 acc[4][4] = {};

    auto stage = [&](int s) {
      const int slot = s & 3;
      const int kt128 = s >> 2;
      const int koff = (s & 3) * 32;
      const u16* baseLo = (kt128 <= tLo) ? Sp_b + ((triLo + kt128) << 14) : ztile;
      const u16* baseHi = Sp_b + ((triHi + kt128) << 14);
#pragma unroll
      for (int i = 0; i < 2; ++i) {
        int p = i * 512 + tid;
        int r = ((p >> 6) << 4) | ((p >> 2) & 15);
        int c = (p & 3) ^ ((p >> 2) & 3);
        const u16* base = i ? baseHi : baseLo; // rows 128-255 <-> i==1
        gld_lds16(base + (size_t)(r & 127) * 128 + koff + c * 8, &LA[slot][p * 8]);
      }
      {
        int p = tid;
        int r = ((p >> 6) << 4) | ((p >> 2) & 15);
        int c = (p & 3) ^ ((p >> 2) & 3);
        gld_lds16(VTb + (size_t)(d0 * 128 + r) * 4096 + s * 32 + c * 8, &LB[slot][p * 8]);
      }
    };

    stage(0); stage(1); stage(2);
    for (int s = 0; s < nsub; ++s) {
      if (s + 3 < nsub) {
        stage(s + 3);
        asm volatile("s_waitcnt vmcnt(9)" ::: "memory");   // 3 stages x 3 loads newer
      } else {
        asm volatile("s_waitcnt vmcnt(0)" ::: "memory");
      }
      __builtin_amdgcn_sched_barrier(0);
      __builtin_amdgcn_s_barrier();
      __builtin_amdgcn_sched_barrier(0);
      {
        const int slot = s & 3;
        const u16* A = LA[slot];
        const u16* B = LB[slot];
        bf16x8 af[4], bf[4];
#pragma unroll
        for (int m = 0; m < 4; ++m)
          af[m] = *(const bf16x8*)&A[(wm * 4 + m) * 512 + roff];
#pragma unroll
        for (int n = 0; n < 4; ++n)
          bf[n] = *(const bf16x8*)&B[(wn * 4 + n) * 512 + roff];
        __builtin_amdgcn_s_setprio(1);
#pragma unroll
        for (int m = 0; m < 4; ++m)
#pragma unroll
          for (int n = 0; n < 4; ++n)
            acc[m][n] = mfma16(af[m], bf[n], acc[m][n]);
        __builtin_amdgcn_s_setprio(0);
      }
      asm volatile("s_waitcnt lgkmcnt(0)" ::: "memory");
      __builtin_amdgcn_sched_barrier(0);
      __builtin_amdgcn_s_barrier();
      __builtin_amdgcn_sched_barrier(0);
    }

    const float* lb = linv + (size_t)b * 4096 + M0;
#pragma unroll
    for (int m = 0; m < 4; ++m) {
#pragma unroll
      for (int r = 0; r < 4; ++r) {
        int rl = wm * 64 + m * 16 + 4 * g + r;
        float li = lb[rl];
#pragma unroll
        for (int n = 0; n < 4; ++n) {
          int dcol = d0 * 128 + wn * 64 + n * 16 + c16;
          Ob[(size_t)(M0 + rl) * 1024 + dcol] = acc[m][n][r] * li;
        }
      }
    }
  }
}

// ---------------- fallback attn (R1, proven 558us) ----------------
__global__ __launch_bounds__(512, 2)
void attn_kernel(const u16* __restrict__ Q, const u16* __restrict__ K,
                 const u16* __restrict__ VT, float* __restrict__ Out) {
  __shared__ u16 kv_lds[32 * 1024];
  __shared__ float s_part[4][32][33];
  __shared__ u16 p_lds[32 * 40];
  __shared__ float l_lds[32];

  const int tid = threadIdx.x;
  const int w = tid >> 6, lane = tid & 63;
  const int g = lane >> 4, c16 = lane & 15;
  const int b  = blockIdx.x & 3;
  const int qb = 127 - (blockIdx.x >> 2);
  const int qs = qb * 32;
  const int kh = w & 1, dq = w >> 1;

  const u16* Qb  = Q  + (size_t)b * 4096 * 1024;
  const u16* Kb  = K  + (size_t)b * 4096 * 1024;
  const u16* VTb = VT + (size_t)b * 1024 * 4096;

  bf16x8 qfrag[2][8];
#pragma unroll
  for (int qh = 0; qh < 2; ++qh)
#pragma unroll
    for (int dk = 0; dk < 8; ++dk)
      qfrag[qh][dk] = *(const bf16x8*)(Qb + (size_t)(qs + qh * 16 + c16) * 1024
                                       + dq * 256 + dk * 32 + g * 8);

  f32x4 oacc[2][8] = {};
  if (tid < 32) l_lds[tid] = 0.f;

  const int qrow_p = tid >> 4;
  const int kk     = tid & 15;
  const int gq     = qs + qrow_p;

  for (int j = 0; j <= qb; ++j) {
    const int kv0 = j * 32;
    __syncthreads();
    uint4 rk[8];
#pragma unroll
    for (int i = 0; i < 8; ++i) {
      int ci = i * 512 + tid;
      int r  = ci >> 7;
      int c  = (ci & 127) ^ (r & 7);
      rk[i] = *(const uint4*)(Kb + (size_t)(kv0 + r) * 1024 + c * 8);
    }
#pragma unroll
    for (int i = 0; i < 8; ++i)
      *(uint4*)&kv_lds[(size_t)(i * 512 + tid) * 8] = rk[i];
    __syncthreads();
    f32x4 sacc[2] = {};
#pragma unroll
    for (int dk = 0; dk < 8; ++dk) {
      int kvrow = kh * 16 + c16;
      int ch    = dq * 32 + dk * 4 + g;
      bf16x8 kf = *(const bf16x8*)&kv_lds[kvrow * 1024 + ((ch ^ (kvrow & 7)) * 8)];
      sacc[0] = mfma16(qfrag[0][dk], kf, sacc[0]);
      sacc[1] = mfma16(qfrag[1][dk], kf, sacc[1]);
    }
#pragma unroll
    for (int qh = 0; qh < 2; ++qh)
#pragma unroll
      for (int r = 0; r < 4; ++r)
        s_part[dq][qh * 16 + 4 * g + r][kh * 16 + c16] = sacc[qh][r];
    __syncthreads();
    uint4 rv[8];
#pragma unroll
    for (int i = 0; i < 8; ++i) {
      int ci = i * 512 + tid;
      int d  = ((ci >> 6) << 4) + (ci & 15);
      int c  = (ci >> 4) & 3;
      rv[i] = *(const uint4*)(VTb + (size_t)d * 4096 + kv0 + c * 8);
    }
    {
      float psum = 0.f;
#pragma unroll
      for (int h = 0; h < 2; ++h) {
        int kcol = kk + h * 16;
        float s = s_part[0][qrow_p][kcol] + s_part[1][qrow_p][kcol]
                + s_part[2][qrow_p][kcol] + s_part[3][qrow_p][kcol];
        s *= 0.03125f;
        float p = (kv0 + kcol <= gq) ? __expf(s) : 0.f;
        u16 pb = f2bf(p);
        p_lds[qrow_p * 40 + kcol] = pb;
        psum += bf2f(pb);
      }
#pragma unroll
      for (int off = 1; off < 16; off <<= 1)
        psum += __shfl_xor(psum, off, 64);
      if (kk == 0) l_lds[qrow_p] += psum;
    }
#pragma unroll
    for (int i = 0; i < 8; ++i)
      *(uint4*)&kv_lds[(size_t)(i * 512 + tid) * 8] = rv[i];
    __syncthreads();
    bf16x8 pa0 = *(const bf16x8*)&p_lds[(0  + c16) * 40 + g * 8];
    bf16x8 pa1 = *(const bf16x8*)&p_lds[(16 + c16) * 40 + g * 8];
#pragma unroll
    for (int f = 0; f < 8; ++f) {
      int dcol = w * 128 + f * 16 + c16;
      int pos  = (dcol >> 4) * 64 + g * 16 + (dcol & 15);
      bf16x8 vf = *(const bf16x8*)&kv_lds[(size_t)pos * 8];
      oacc[0][f] = mfma16(pa0, vf, oacc[0][f]);
      oacc[1][f] = mfma16(pa1, vf, oacc[1][f]);
    }
  }

  float* Ob = Out + (size_t)b * 4096 * 1024;
#pragma unroll
  for (int qh = 0; qh < 2; ++qh) {
#pragma unroll
    for (int r = 0; r < 4; ++r) {
      int ql = qh * 16 + 4 * g + r;
      float linvv = 1.f / l_lds[ql];
#pragma unroll
      for (int f = 0; f < 8; ++f)
        Ob[(size_t)(qs + ql) * 1024 + w * 128 + f * 16 + c16] = oacc[qh][f][r] * linvv;
    }
  }
}

extern "C" void kernel_launch(void* const* d_in, const int* in_sizes, int n_in,
                              void* d_out, int out_size, void* d_ws, size_t ws_size,
                              hipStream_t stream) {
  const float* x  = (const float*)d_in[0];
  const float* Wq = (const float*)d_in[1];
  const float* Wk = (const float*)d_in[2];
  const float* Wv = (const float*)d_in[3];
  float* out = (float*)d_out;

  u16* ws    = (u16*)d_ws;
  u16* wWqkv = ws;                                   // 3M elems
  u16* wX    = wWqkv + (size_t)3 * 1024 * 1024;      // dead after qkv -> zero tile
  u16* wQ    = wX + (size_t)16384 * 1024;
  u16* wK    = wQ + (size_t)16384 * 1024;
  u16* wVT   = wK + (size_t)16384 * 1024;            // [4][1024][4096]
  u16* wSp   = wVT + (size_t)16384 * 1024;           // packed 128-tile triangle
  float* lpart = (float*)(ws + (size_t)104857600);   // 16384*16 f32 (1MB)
  float* linv  = (float*)(ws + (size_t)105906176);   // 16384 f32

  cast_f32_bf16<<<dim3(8192), 256, 0, stream>>>(x, wX, 16777216 / 8);
  cast_f32_bf16<<<dim3(512), 256, 0, stream>>>(Wq, wWqkv,                 1048576 / 8);
  cast_f32_bf16<<<dim3(512), 256, 0, stream>>>(Wk, wWqkv + 1048576,       1048576 / 8);
  cast_f32_bf16<<<dim3(512), 256, 0, stream>>>(Wv, wWqkv + 2 * 1048576,   1048576 / 8);

  qkv_gemm<<<dim3(64, 12), 512, 0, stream>>>(wX, wWqkv, wQ, wK, wVT);

  if (ws_size >= (size_t)211877888) {
    hipMemsetAsync(wX, 0, 32768, stream);            // zero tile for absent causal tiles
    sgemm_exp<<<dim3(136, 4), 512, 0, stream>>>(wQ, wK, wSp, lpart);
    lreduce<<<dim3(64), 256, 0, stream>>>(lpart, linv);
    pv_gemm<<<dim3(8, 8, 4), 512, 0, stream>>>(wSp, wVT, wX, linv, out);
  } else {
    attn_kernel<<<dim3(512), 512, 0, stream>>>(wQ, wK, wVT, out);
  }
}

// Round 7
// 407.094 us; speedup vs baseline: 1.1356x; 1.1356x over previous
//
#include <hip/hip_runtime.h>

// CausalAttention: B=4, S=4096, D=1024 (single head, head_dim=1024)
// v7: cast -> QKV GEMM (VT) -> S-GEMM+exp (packed causal triangle, bf16)
//     -> l-reduce -> PV GEMM (scale 1/l). No-max softmax (validated R1).
// R7: R5's proven 256-tile dbuf structure + conflict-free XOR layout, with
// the sync restructured to counted vmcnt (T4): all 8 gld of tile t+1 issued
// at tile t's acquire (after t-1's release barrier, same WAR guarantee as
// R5's syncthreads), then vmcnt(8) waits only for tile t's loads (issued a
// full tile earlier -> latency covered). Compute paced into 4 phases of
// 16 MFMA (T3), setprio around MFMA (T5), lgkmcnt(0) closes each phase.
// ws (u16 elems): Wqkv[3M] | X[16M, reused as zero-tile] | Q[16M] | K[16M] |
//   VT[16M] | Spack[34.6M packed 128-tiles] | lpart | linv

typedef unsigned short u16;
typedef unsigned int u32;
typedef __attribute__((ext_vector_type(8))) short bf16x8;
typedef __attribute__((ext_vector_type(4))) float f32x4;
typedef __attribute__((ext_vector_type(8))) unsigned short u16x8;

__device__ __forceinline__ u16 f2bf(float f) {
  union { float f; unsigned u; } v; v.f = f;
  unsigned r = v.u + 0x7FFFu + ((v.u >> 16) & 1u);  // RNE
  return (u16)(r >> 16);
}
__device__ __forceinline__ float bf2f(u16 h) {
  union { unsigned u; float f; } v; v.u = ((unsigned)h) << 16;
  return v.f;
}
__device__ __forceinline__ f32x4 mfma16(bf16x8 a, bf16x8 b, f32x4 c) {
  return __builtin_amdgcn_mfma_f32_16x16x32_bf16(a, b, c, 0, 0, 0);
}
__device__ __forceinline__ void gld_lds16(const u16* g, u16* l) {
  __builtin_amdgcn_global_load_lds(
      (const __attribute__((address_space(1))) u32*)g,
      (__attribute__((address_space(3))) u32*)l, 16, 0, 0);
}
#define PHASE_END() do {                                   \
    asm volatile("s_waitcnt lgkmcnt(0)" ::: "memory");     \
    __builtin_amdgcn_sched_barrier(0);                     \
    __builtin_amdgcn_s_barrier();                          \
    __builtin_amdgcn_sched_barrier(0);                     \
  } while (0)

// ---------------- cast f32 -> bf16, 8 elems/thread ----------------
__global__ __launch_bounds__(256)
void cast_f32_bf16(const float* __restrict__ src, u16* __restrict__ dst, int n8) {
  int i = blockIdx.x * 256 + threadIdx.x;
  if (i >= n8) return;
  const float4* s4 = (const float4*)src;
  float4 a = s4[2*i], b = s4[2*i+1];
  u16x8 o;
  o[0]=f2bf(a.x); o[1]=f2bf(a.y); o[2]=f2bf(a.z); o[3]=f2bf(a.w);
  o[4]=f2bf(b.x); o[5]=f2bf(b.y); o[6]=f2bf(b.z); o[7]=f2bf(b.w);
  ((u16x8*)dst)[i] = o;
}

// ---------------- fused QKV GEMM: 256x256, dbuf + counted vmcnt ----------------
__global__ __launch_bounds__(512)
void qkv_gemm(const u16* __restrict__ X, const u16* __restrict__ W,
              u16* __restrict__ Qo, u16* __restrict__ Ko, u16* __restrict__ VTo) {
  __shared__ __align__(16) u16 At[2][256 * 64];
  __shared__ __align__(16) u16 Bt[2][256 * 64];
  const int tid = threadIdx.x;
  const int w = tid >> 6, lane = tid & 63;
  const int g = lane >> 4, c16 = lane & 15;
  const int wr = w >> 2, wc = w & 3;           // wave out: rows wr*128, cols wc*64
  const int M0 = blockIdx.x * 256;
  const int N0 = blockIdx.y * 256;

  f32x4 acc[8][4] = {};

  auto stage = [&](int s, int k0) {
#pragma unroll
    for (int i = 0; i < 4; ++i) {
      int ci = i * 512 + tid;                  // lane-linear chunk id (2048/tile)
      int r = ci >> 3;
      int c = (ci & 7) ^ (r & 7);              // pre-swizzled source chunk
      gld_lds16(X + (size_t)(M0 + r) * 1024 + k0 + c * 8, &At[s][ci * 8]);
    }
#pragma unroll
    for (int i = 0; i < 4; ++i) {
      int ci = i * 512 + tid;
      int r = ci >> 3;
      int c = (ci & 7) ^ (r & 7);
      gld_lds16(W + (size_t)(N0 + r) * 1024 + k0 + c * 8, &Bt[s][ci * 8]);
    }
  };

  stage(0, 0);
  for (int t = 0; t < 16; ++t) {
    const int buf = t & 1;
    // ---- acquire: issue next-tile loads, counted wait for current tile ----
    if (t < 15) {
      stage(buf ^ 1, (t + 1) * 64);
      asm volatile("s_waitcnt vmcnt(8)" ::: "memory");
    } else {
      asm volatile("s_waitcnt vmcnt(0)" ::: "memory");
    }
    __builtin_amdgcn_sched_barrier(0);
    __builtin_amdgcn_s_barrier();
    __builtin_amdgcn_sched_barrier(0);
    const u16* A = At[buf];
    const u16* B = Bt[buf];
#pragma unroll
    for (int dk = 0; dk < 2; ++dk) {
      const int ch = dk * 4 + g;
      bf16x8 bfr[4], af[4];
#pragma unroll
      for (int n = 0; n < 4; ++n) {
        int row = wc * 64 + n * 16 + c16;
        bfr[n] = *(const bf16x8*)&B[row * 64 + ((ch ^ (row & 7)) * 8)];
      }
      // phase A: m 0..3
#pragma unroll
      for (int m = 0; m < 4; ++m) {
        int row = wr * 128 + m * 16 + c16;
        af[m] = *(const bf16x8*)&A[row * 64 + ((ch ^ (row & 7)) * 8)];
      }
      __builtin_amdgcn_s_setprio(1);
#pragma unroll
      for (int m = 0; m < 4; ++m)
#pragma unroll
        for (int n = 0; n < 4; ++n)
          acc[m][n] = mfma16(af[m], bfr[n], acc[m][n]);
      __builtin_amdgcn_s_setprio(0);
      PHASE_END();
      // phase B: m 4..7
#pragma unroll
      for (int m = 0; m < 4; ++m) {
        int row = wr * 128 + (m + 4) * 16 + c16;
        af[m] = *(const bf16x8*)&A[row * 64 + ((ch ^ (row & 7)) * 8)];
      }
      __builtin_amdgcn_s_setprio(1);
#pragma unroll
      for (int m = 0; m < 4; ++m)
#pragma unroll
        for (int n = 0; n < 4; ++n)
          acc[m + 4][n] = mfma16(af[m], bfr[n], acc[m + 4][n]);
      __builtin_amdgcn_s_setprio(0);
      PHASE_END();
    }
  }

  const int which = N0 >> 10;                  // 0=Q, 1=K, 2=V
  const int colbase = N0 & 1023;
#pragma unroll
  for (int m = 0; m < 8; ++m) {
#pragma unroll
    for (int n = 0; n < 4; ++n) {
#pragma unroll
      for (int r = 0; r < 4; ++r) {
        int gm  = M0 + wr * 128 + m * 16 + 4 * g + r;
        int col = colbase + wc * 64 + n * 16 + c16;
        u16 hv = f2bf(acc[m][n][r]);
        if (which == 0) {
          Qo[(size_t)gm * 1024 + col] = hv;
        } else if (which == 1) {
          Ko[(size_t)gm * 1024 + col] = hv;
        } else {
          int b = gm >> 12, s2 = gm & 4095;
          VTo[((size_t)((b << 10) + col)) * 4096 + s2] = hv;
        }
      }
    }
  }
}

// ---------------- S-GEMM + exp: 256x256 causal tiles ----------------
__global__ __launch_bounds__(512)
void sgemm_exp(const u16* __restrict__ Q, const u16* __restrict__ K,
               u16* __restrict__ Spack, float* __restrict__ lpart) {
  __shared__ __align__(16) u16 At[2][256 * 64];
  __shared__ __align__(16) u16 Bt[2][256 * 64];
  __shared__ float lsum[256][4];
  const int tid = threadIdx.x;
  const int w = tid >> 6, lane = tid & 63;
  const int g = lane >> 4, c16 = lane & 15;
  const int wr = w >> 2, wc = w & 3;
  const int b = blockIdx.y;

  int L = blockIdx.x, qt = 0;                  // triangular decode
  while ((qt + 1) * (qt + 2) / 2 <= L) ++qt;
  const int kt = L - qt * (qt + 1) / 2;

  const u16* Qb = Q + (size_t)b * 4096 * 1024 + (size_t)qt * 256 * 1024;
  const u16* Kb = K + (size_t)b * 4096 * 1024 + (size_t)kt * 256 * 1024;

  f32x4 acc[8][4] = {};

  auto stage = [&](int s, int k0) {
#pragma unroll
    for (int i = 0; i < 4; ++i) {
      int ci = i * 512 + tid;
      int r = ci >> 3;
      int c = (ci & 7) ^ (r & 7);
      gld_lds16(Qb + (size_t)r * 1024 + k0 + c * 8, &At[s][ci * 8]);
    }
#pragma unroll
    for (int i = 0; i < 4; ++i) {
      int ci = i * 512 + tid;
      int r = ci >> 3;
      int c = (ci & 7) ^ (r & 7);
      gld_lds16(Kb + (size_t)r * 1024 + k0 + c * 8, &Bt[s][ci * 8]);
    }
  };

  stage(0, 0);
  for (int t = 0; t < 16; ++t) {
    const int buf = t & 1;
    if (t < 15) {
      stage(buf ^ 1, (t + 1) * 64);
      asm volatile("s_waitcnt vmcnt(8)" ::: "memory");
    } else {
      asm volatile("s_waitcnt vmcnt(0)" ::: "memory");
    }
    __builtin_amdgcn_sched_barrier(0);
    __builtin_amdgcn_s_barrier();
    __builtin_amdgcn_sched_barrier(0);
    const u16* A = At[buf];
    const u16* B = Bt[buf];
#pragma unroll
    for (int dk = 0; dk < 2; ++dk) {
      const int ch = dk * 4 + g;
      bf16x8 bfr[4], af[4];
#pragma unroll
      for (int n = 0; n < 4; ++n) {
        int row = wc * 64 + n * 16 + c16;
        bfr[n] = *(const bf16x8*)&B[row * 64 + ((ch ^ (row & 7)) * 8)];
      }
#pragma unroll
      for (int m = 0; m < 4; ++m) {
        int row = wr * 128 + m * 16 + c16;
        af[m] = *(const bf16x8*)&A[row * 64 + ((ch ^ (row & 7)) * 8)];
      }
      __builtin_amdgcn_s_setprio(1);
#pragma unroll
      for (int m = 0; m < 4; ++m)
#pragma unroll
        for (int n = 0; n < 4; ++n)
          acc[m][n] = mfma16(af[m], bfr[n], acc[m][n]);
      __builtin_amdgcn_s_setprio(0);
      PHASE_END();
#pragma unroll
      for (int m = 0; m < 4; ++m) {
        int row = wr * 128 + (m + 4) * 16 + c16;
        af[m] = *(const bf16x8*)&A[row * 64 + ((ch ^ (row & 7)) * 8)];
      }
      __builtin_amdgcn_s_setprio(1);
#pragma unroll
      for (int m = 0; m < 4; ++m)
#pragma unroll
        for (int n = 0; n < 4; ++n)
          acc[m + 4][n] = mfma16(af[m], bfr[n], acc[m + 4][n]);
      __builtin_amdgcn_s_setprio(0);
      PHASE_END();
    }
  }

  // epilogue: exp + mask, store into 128-tile packed layout, row-sum partials.
  const int qt128 = 2 * qt + wr;
  const int kt128 = 2 * kt + (wc >> 1);
  const bool exists = (kt128 <= qt128);
  u16* Sb = Spack + (((size_t)b * 528 + (size_t)(qt128 * (qt128 + 1)) / 2 + kt128) << 14);
  const int q0 = qt * 256, k0g = kt * 256;
  float psum[8][4];
#pragma unroll
  for (int m = 0; m < 8; ++m)
#pragma unroll
    for (int r = 0; r < 4; ++r) psum[m][r] = 0.f;
#pragma unroll
  for (int m = 0; m < 8; ++m) {
#pragma unroll
    for (int n = 0; n < 4; ++n) {
#pragma unroll
      for (int r = 0; r < 4; ++r) {
        int rl = wr * 128 + m * 16 + 4 * g + r;
        int cl = wc * 64 + n * 16 + c16;
        float s = acc[m][n][r] * 0.03125f;     // 1/sqrt(1024)
        float p = (k0g + cl <= q0 + rl) ? __expf(s) : 0.f;
        u16 pb = f2bf(p);
        if (exists) Sb[(rl & 127) * 128 + (cl & 127)] = pb;
        psum[m][r] += bf2f(pb);
      }
    }
  }
#pragma unroll
  for (int m = 0; m < 8; ++m)
#pragma unroll
    for (int r = 0; r < 4; ++r) {
      float v = psum[m][r];
      v += __shfl_xor(v, 1, 64);
      v += __shfl_xor(v, 2, 64);
      v += __shfl_xor(v, 4, 64);
      v += __shfl_xor(v, 8, 64);
      psum[m][r] = v;
    }
  if (c16 == 0) {
#pragma unroll
    for (int m = 0; m < 8; ++m)
#pragma unroll
      for (int r = 0; r < 4; ++r)
        lsum[wr * 128 + m * 16 + 4 * g + r][wc] = psum[m][r];
  }
  __syncthreads();
  if (tid < 256) {
    float v = lsum[tid][0] + lsum[tid][1] + lsum[tid][2] + lsum[tid][3];
    lpart[((size_t)b * 4096 + q0 + tid) * 16 + kt] = v;
  }
}

// ---------------- l reduction -> 1/l ----------------
__global__ __launch_bounds__(256)
void lreduce(const float* __restrict__ lpart, float* __restrict__ linv) {
  int row = blockIdx.x * 256 + threadIdx.x;    // 0..16383
  int nt  = ((row & 4095) >> 8) + 1;           // valid 256-col partials
  const float* p = lpart + (size_t)row * 16;
  float s = 0.f;
  for (int i = 0; i < nt; ++i) s += p[i];
  linv[row] = 1.f / s;
}

// ---------------- PV GEMM: 256x128 paired q-tiles ----------------
__global__ __launch_bounds__(512)
void pv_gemm(const u16* __restrict__ Spack, const u16* __restrict__ VT,
             const u16* __restrict__ ztile, const float* __restrict__ linv,
             float* __restrict__ Out) {
  __shared__ __align__(16) u16 At[2][256 * 64];
  __shared__ __align__(16) u16 Bt[2][128 * 64];
  const int tid = threadIdx.x;
  const int w = tid >> 6, lane = tid & 63;
  const int g = lane >> 4, c16 = lane & 15;
  const int wm = w >> 1, wn = w & 1;           // wave out: rows wm*64, cols wn*64
  const int pp = blockIdx.x;
  const int d0 = blockIdx.y;
  const int b  = blockIdx.z;

  const u16* Sp_b = Spack + (size_t)b * 528 * 16384;
  const u16* VTb  = VT + (size_t)b * 1024 * 4096;
  float* Ob = Out + (size_t)b * 4096 * 1024;

  for (int pass = 0; pass < 2; ++pass) {
    const int QT = pass == 0 ? pp : 15 - pp;
    const int M0 = QT * 256;
    const int nsteps = (QT + 1) * 4;
    const int tLo = 2 * QT;
    const size_t triLo = (size_t)(tLo * (tLo + 1)) / 2;
    const size_t triHi = (size_t)((tLo + 1) * (tLo + 2)) / 2;

    f32x4 acc[4][4] = {};

    auto stage = [&](int s, int tt) {
      const int kv0 = tt * 64;
      const int kt128 = tt >> 1;
      const int koff = (tt & 1) * 64;
      const u16* baseLo = (kt128 <= tLo) ? Sp_b + ((triLo + kt128) << 14) : ztile;
      const u16* baseHi = Sp_b + ((triHi + kt128) << 14);
#pragma unroll
      for (int i = 0; i < 4; ++i) {
        int ci = i * 512 + tid;
        int r = ci >> 3;
        int c = (ci & 7) ^ (r & 7);
        const u16* base = (i < 2) ? baseLo : baseHi;
        gld_lds16(base + (size_t)(r & 127) * 128 + koff + c * 8, &At[s][ci * 8]);
      }
#pragma unroll
      for (int i = 0; i < 2; ++i) {
        int ci = i * 512 + tid;
        int r = ci >> 3;
        int c = (ci & 7) ^ (r & 7);
        gld_lds16(VTb + (size_t)(d0 * 128 + r) * 4096 + kv0 + c * 8, &Bt[s][ci * 8]);
      }
    };

    stage(0, 0);
    for (int t = 0; t < nsteps; ++t) {
      const int buf = t & 1;
      if (t + 1 < nsteps) {
        stage(buf ^ 1, t + 1);
        asm volatile("s_waitcnt vmcnt(6)" ::: "memory");
      } else {
        asm volatile("s_waitcnt vmcnt(0)" ::: "memory");
      }
      __builtin_amdgcn_sched_barrier(0);
      __builtin_amdgcn_s_barrier();
      __builtin_amdgcn_sched_barrier(0);
      const u16* A = At[buf];
      const u16* B = Bt[buf];
#pragma unroll
      for (int dk = 0; dk < 2; ++dk) {
        const int ch = dk * 4 + g;
        bf16x8 af[4], bfr[4];
#pragma unroll
        for (int m = 0; m < 4; ++m) {
          int row = wm * 64 + m * 16 + c16;
          af[m] = *(const bf16x8*)&A[row * 64 + ((ch ^ (row & 7)) * 8)];
        }
#pragma unroll
        for (int n = 0; n < 4; ++n) {
          int row = wn * 64 + n * 16 + c16;
          bfr[n] = *(const bf16x8*)&B[row * 64 + ((ch ^ (row & 7)) * 8)];
        }
        __builtin_amdgcn_s_setprio(1);
#pragma unroll
        for (int m = 0; m < 4; ++m)
#pragma unroll
          for (int n = 0; n < 4; ++n)
            acc[m][n] = mfma16(af[m], bfr[n], acc[m][n]);
        __builtin_amdgcn_s_setprio(0);
        PHASE_END();
      }
    }

    const float* lb = linv + (size_t)b * 4096 + M0;
#pragma unroll
    for (int m = 0; m < 4; ++m) {
#pragma unroll
      for (int r = 0; r < 4; ++r) {
        int rl = wm * 64 + m * 16 + 4 * g + r;
        float li = lb[rl];
#pragma unroll
        for (int n = 0; n < 4; ++n) {
          int dcol = d0 * 128 + wn * 64 + n * 16 + c16;
          Ob[(size_t)(M0 + rl) * 1024 + dcol] = acc[m][n][r] * li;
        }
      }
    }
  }
}

// ---------------- fallback attn (R1, proven 558us) ----------------
__global__ __launch_bounds__(512, 2)
void attn_kernel(const u16* __restrict__ Q, const u16* __restrict__ K,
                 const u16* __restrict__ VT, float* __restrict__ Out) {
  __shared__ u16 kv_lds[32 * 1024];
  __shared__ float s_part[4][32][33];
  __shared__ u16 p_lds[32 * 40];
  __shared__ float l_lds[32];

  const int tid = threadIdx.x;
  const int w = tid >> 6, lane = tid & 63;
  const int g = lane >> 4, c16 = lane & 15;
  const int b  = blockIdx.x & 3;
  const int qb = 127 - (blockIdx.x >> 2);
  const int qs = qb * 32;
  const int kh = w & 1, dq = w >> 1;

  const u16* Qb  = Q  + (size_t)b * 4096 * 1024;
  const u16* Kb  = K  + (size_t)b * 4096 * 1024;
  const u16* VTb = VT + (size_t)b * 1024 * 4096;

  bf16x8 qfrag[2][8];
#pragma unroll
  for (int qh = 0; qh < 2; ++qh)
#pragma unroll
    for (int dk = 0; dk < 8; ++dk)
      qfrag[qh][dk] = *(const bf16x8*)(Qb + (size_t)(qs + qh * 16 + c16) * 1024
                                       + dq * 256 + dk * 32 + g * 8);

  f32x4 oacc[2][8] = {};
  if (tid < 32) l_lds[tid] = 0.f;

  const int qrow_p = tid >> 4;
  const int kk     = tid & 15;
  const int gq     = qs + qrow_p;

  for (int j = 0; j <= qb; ++j) {
    const int kv0 = j * 32;
    __syncthreads();
    uint4 rk[8];
#pragma unroll
    for (int i = 0; i < 8; ++i) {
      int ci = i * 512 + tid;
      int r  = ci >> 7;
      int c  = (ci & 127) ^ (r & 7);
      rk[i] = *(const uint4*)(Kb + (size_t)(kv0 + r) * 1024 + c * 8);
    }
#pragma unroll
    for (int i = 0; i < 8; ++i)
      *(uint4*)&kv_lds[(size_t)(i * 512 + tid) * 8] = rk[i];
    __syncthreads();
    f32x4 sacc[2] = {};
#pragma unroll
    for (int dk = 0; dk < 8; ++dk) {
      int kvrow = kh * 16 + c16;
      int ch    = dq * 32 + dk * 4 + g;
      bf16x8 kf = *(const bf16x8*)&kv_lds[kvrow * 1024 + ((ch ^ (kvrow & 7)) * 8)];
      sacc[0] = mfma16(qfrag[0][dk], kf, sacc[0]);
      sacc[1] = mfma16(qfrag[1][dk], kf, sacc[1]);
    }
#pragma unroll
    for (int qh = 0; qh < 2; ++qh)
#pragma unroll
      for (int r = 0; r < 4; ++r)
        s_part[dq][qh * 16 + 4 * g + r][kh * 16 + c16] = sacc[qh][r];
    __syncthreads();
    uint4 rv[8];
#pragma unroll
    for (int i = 0; i < 8; ++i) {
      int ci = i * 512 + tid;
      int d  = ((ci >> 6) << 4) + (ci & 15);
      int c  = (ci >> 4) & 3;
      rv[i] = *(const uint4*)(VTb + (size_t)d * 4096 + kv0 + c * 8);
    }
    {
      float psum = 0.f;
#pragma unroll
      for (int h = 0; h < 2; ++h) {
        int kcol = kk + h * 16;
        float s = s_part[0][qrow_p][kcol] + s_part[1][qrow_p][kcol]
                + s_part[2][qrow_p][kcol] + s_part[3][qrow_p][kcol];
        s *= 0.03125f;
        float p = (kv0 + kcol <= gq) ? __expf(s) : 0.f;
        u16 pb = f2bf(p);
        p_lds[qrow_p * 40 + kcol] = pb;
        psum += bf2f(pb);
      }
#pragma unroll
      for (int off = 1; off < 16; off <<= 1)
        psum += __shfl_xor(psum, off, 64);
      if (kk == 0) l_lds[qrow_p] += psum;
    }
#pragma unroll
    for (int i = 0; i < 8; ++i)
      *(uint4*)&kv_lds[(size_t)(i * 512 + tid) * 8] = rv[i];
    __syncthreads();
    bf16x8 pa0 = *(const bf16x8*)&p_lds[(0  + c16) * 40 + g * 8];
    bf16x8 pa1 = *(const bf16x8*)&p_lds[(16 + c16) * 40 + g * 8];
#pragma unroll
    for (int f = 0; f < 8; ++f) {
      int dcol = w * 128 + f * 16 + c16;
      int pos  = (dcol >> 4) * 64 + g * 16 + (dcol & 15);
      bf16x8 vf = *(const bf16x8*)&kv_lds[(size_t)pos * 8];
      oacc[0][f] = mfma16(pa0, vf, oacc[0][f]);
      oacc[1][f] = mfma16(pa1, vf, oacc[1][f]);
    }
  }

  float* Ob = Out + (size_t)b * 4096 * 1024;
#pragma unroll
  for (int qh = 0; qh < 2; ++qh) {
#pragma unroll
    for (int r = 0; r < 4; ++r) {
      int ql = qh * 16 + 4 * g + r;
      float linvv = 1.f / l_lds[ql];
#pragma unroll
      for (int f = 0; f < 8; ++f)
        Ob[(size_t)(qs + ql) * 1024 + w * 128 + f * 16 + c16] = oacc[qh][f][r] * linvv;
    }
  }
}

extern "C" void kernel_launch(void* const* d_in, const int* in_sizes, int n_in,
                              void* d_out, int out_size, void* d_ws, size_t ws_size,
                              hipStream_t stream) {
  const float* x  = (const float*)d_in[0];
  const float* Wq = (const float*)d_in[1];
  const float* Wk = (const float*)d_in[2];
  const float* Wv = (const float*)d_in[3];
  float* out = (float*)d_out;

  u16* ws    = (u16*)d_ws;
  u16* wWqkv = ws;                                   // 3M elems
  u16* wX    = wWqkv + (size_t)3 * 1024 * 1024;      // dead after qkv -> zero tile
  u16* wQ    = wX + (size_t)16384 * 1024;
  u16* wK    = wQ + (size_t)16384 * 1024;
  u16* wVT   = wK + (size_t)16384 * 1024;            // [4][1024][4096]
  u16* wSp   = wVT + (size_t)16384 * 1024;           // packed 128-tile triangle
  float* lpart = (float*)(ws + (size_t)104857600);   // 16384*16 f32 (1MB)
  float* linv  = (float*)(ws + (size_t)105906176);   // 16384 f32

  cast_f32_bf16<<<dim3(8192), 256, 0, stream>>>(x, wX, 16777216 / 8);
  cast_f32_bf16<<<dim3(512), 256, 0, stream>>>(Wq, wWqkv,                 1048576 / 8);
  cast_f32_bf16<<<dim3(512), 256, 0, stream>>>(Wk, wWqkv + 1048576,       1048576 / 8);
  cast_f32_bf16<<<dim3(512), 256, 0, stream>>>(Wv, wWqkv + 2 * 1048576,   1048576 / 8);

  qkv_gemm<<<dim3(64, 12), 512, 0, stream>>>(wX, wWqkv, wQ, wK, wVT);

  if (ws_size >= (size_t)211877888) {
    hipMemsetAsync(wX, 0, 32768, stream);            // zero tile for absent causal tiles
    sgemm_exp<<<dim3(136, 4), 512, 0, stream>>>(wQ, wK, wSp, lpart);
    lreduce<<<dim3(64), 256, 0, stream>>>(lpart, linv);
    pv_gemm<<<dim3(8, 8, 4), 512, 0, stream>>>(wSp, wVT, wX, linv, out);
  } else {
    attn_kernel<<<dim3(512), 512, 0, stream>>>(wQ, wK, wVT, out);
  }
}

// Round 8
// 398.705 us; speedup vs baseline: 1.1595x; 1.0210x over previous
//
#include <hip/hip_runtime.h>

// CausalAttention: B=4, S=4096, D=1024 (single head, head_dim=1024)
// v8: cast -> QKV GEMM (VT) -> S-GEMM+exp (packed causal triangle, bf16)
//     -> l-reduce -> PV GEMM (scale 1/l). No-max softmax (validated R1).
// R8: qkv+sgemm ported to the m201 8-phase template (proven 1563 TF @4k):
// per phase {ds-read subtile + stage 1 half-tile -> s_barrier -> lgkmcnt(0)
// -> setprio(1) 16 MFMA setprio(0) -> s_barrier}; vmcnt(2) only at phases
// 4/8 (counted, never drained mid-loop). Half-tile stage mapping derived
// from read-free points: ph1-3 stage K-tile 2i+1 (B-hi,A-lo,A-hi), ph4-7
// stage 2i+2 (B-lo,B-hi,A-lo,A-hi), ph8 stages 2i+3 B-lo. Per-wave
// vmcnt(2)-before-barrier => all waves' 8 oldest loads retired = exactly
// the buffer needed next. pv_gemm = R5's proven structure (risk isolation).
// ws (u16 elems): Wqkv[3M] | X[16M, zero-tile after qkv] | Q[16M] | K[16M] |
//   VT[16M] | Spack[34.6M packed 128-tiles] | lpart | linv

typedef unsigned short u16;
typedef unsigned int u32;
typedef __attribute__((ext_vector_type(8))) short bf16x8;
typedef __attribute__((ext_vector_type(4))) float f32x4;
typedef __attribute__((ext_vector_type(8))) unsigned short u16x8;

__device__ __forceinline__ u16 f2bf(float f) {
  union { float f; unsigned u; } v; v.f = f;
  unsigned r = v.u + 0x7FFFu + ((v.u >> 16) & 1u);  // RNE
  return (u16)(r >> 16);
}
__device__ __forceinline__ float bf2f(u16 h) {
  union { unsigned u; float f; } v; v.u = ((unsigned)h) << 16;
  return v.f;
}
__device__ __forceinline__ f32x4 mfma16(bf16x8 a, bf16x8 b, f32x4 c) {
  return __builtin_amdgcn_mfma_f32_16x16x32_bf16(a, b, c, 0, 0, 0);
}
__device__ __forceinline__ void gld_lds16(const u16* g, u16* l) {
  __builtin_amdgcn_global_load_lds(
      (const __attribute__((address_space(1))) u32*)g,
      (__attribute__((address_space(3))) u32*)l, 16, 0, 0);
}
#define BAR() __builtin_amdgcn_s_barrier()
#define LGKM0() do { asm volatile("s_waitcnt lgkmcnt(0)" ::: "memory"); \
                     __builtin_amdgcn_sched_barrier(0); } while (0)
#define VMCNT2() asm volatile("s_waitcnt vmcnt(2)" ::: "memory")
#define VMCNT0() asm volatile("s_waitcnt vmcnt(0)" ::: "memory")

// ---------------- cast f32 -> bf16, 8 elems/thread ----------------
__global__ __launch_bounds__(256)
void cast_f32_bf16(const float* __restrict__ src, u16* __restrict__ dst, int n8) {
  int i = blockIdx.x * 256 + threadIdx.x;
  if (i >= n8) return;
  const float4* s4 = (const float4*)src;
  float4 a = s4[2*i], b = s4[2*i+1];
  u16x8 o;
  o[0]=f2bf(a.x); o[1]=f2bf(a.y); o[2]=f2bf(a.z); o[3]=f2bf(a.w);
  o[4]=f2bf(b.x); o[5]=f2bf(b.y); o[6]=f2bf(b.z); o[7]=f2bf(b.w);
  ((u16x8*)dst)[i] = o;
}

// 8-phase GEMM core shared by qkv_gemm / sgemm_exp (identical geometry):
// Abase/Bbase are 256-row x 1024-col bf16 panels (row stride 1024).
// acc[8][4] per wave (wr 2M x wc 4N, per-wave C = 128x64).
#define GEMM8_CORE(Abase, Bbase)                                              \
  auto stageA = [&](int bufi, int h, int t) {                                 \
    _Pragma("unroll")                                                         \
    for (int i = 0; i < 2; ++i) {                                             \
      int ci = i * 512 + tid;                                                 \
      int r  = ci >> 3;                                                       \
      int c  = (ci & 7) ^ (r & 7);                                            \
      gld_lds16(Abase + (size_t)(h * 128 + r) * 1024 + t * 64 + c * 8,        \
                &At[bufi][h][ci * 8]);                                        \
    }                                                                         \
  };                                                                          \
  auto stageB = [&](int bufi, int h, int t) {                                 \
    _Pragma("unroll")                                                         \
    for (int i = 0; i < 2; ++i) {                                             \
      int ci = i * 512 + tid;                                                 \
      int r  = ci >> 3;                                                       \
      int c  = (ci & 7) ^ (r & 7);                                            \
      gld_lds16(Bbase + (size_t)(h * 128 + r) * 1024 + t * 64 + c * 8,        \
                &Bt[bufi][h][ci * 8]);                                        \
    }                                                                         \
  };                                                                          \
  bf16x8 af[4][2], bfr[2][2];                                                 \
  auto readA = [&](int bufi, int mb) {                                        \
    _Pragma("unroll")                                                         \
    for (int m = 0; m < 4; ++m)                                               \
      _Pragma("unroll")                                                       \
      for (int dk = 0; dk < 2; ++dk) {                                        \
        int r  = (mb + m) * 16 + c16;                                         \
        int ch = dk * 4 + g;                                                  \
        af[m][dk] = *(const bf16x8*)&At[bufi][wr][r * 64 + ((ch ^ (r & 7)) * 8)]; \
      }                                                                       \
  };                                                                          \
  auto readB = [&](int bufi, int nb) {                                        \
    _Pragma("unroll")                                                         \
    for (int n = 0; n < 2; ++n)                                               \
      _Pragma("unroll")                                                       \
      for (int dk = 0; dk < 2; ++dk) {                                        \
        int r  = (wc & 1) * 64 + (nb + n) * 16 + c16;                         \
        int ch = dk * 4 + g;                                                  \
        bfr[n][dk] = *(const bf16x8*)&Bt[bufi][wc >> 1][r * 64 + ((ch ^ (r & 7)) * 8)]; \
      }                                                                       \
  };                                                                          \
  auto domfma = [&](int mb, int nb) {                                         \
    __builtin_amdgcn_s_setprio(1);                                            \
    _Pragma("unroll")                                                         \
    for (int dk = 0; dk < 2; ++dk)                                            \
      _Pragma("unroll")                                                       \
      for (int m = 0; m < 4; ++m)                                             \
        _Pragma("unroll")                                                     \
        for (int n = 0; n < 2; ++n)                                           \
          acc[mb + m][nb + n] = mfma16(af[m][dk], bfr[n][dk], acc[mb + m][nb + n]); \
    __builtin_amdgcn_s_setprio(0);                                            \
  };                                                                          \
  /* prologue: K-tile0 full into buf0, K-tile1 B-lo into buf1 */              \
  stageB(0, 0, 0); stageB(0, 1, 0); stageA(0, 0, 0); stageA(0, 1, 0);         \
  stageB(1, 0, 1);                                                            \
  VMCNT2();                                                                   \
  BAR();                                                                      \
  for (int it = 0; it < 8; ++it) {                                            \
    const bool pf = (it < 7);                                                 \
    const int t1 = 2 * it + 1, t2 = 2 * it + 2, t3 = 2 * it + 3;              \
    /* P1: buf0 Q0 (m0-3 x n0-1) */                                           \
    readA(0, 0); readB(0, 0);                                                 \
    stageB(1, 1, t1);                                                         \
    BAR(); LGKM0();                                                           \
    domfma(0, 0);                                                             \
    BAR();                                                                    \
    /* P2: Q1 (m4-7 x n0-1) */                                                \
    readA(0, 4);                                                              \
    stageA(1, 0, t1);                                                         \
    BAR(); LGKM0();                                                           \
    domfma(4, 0);                                                             \
    BAR();                                                                    \
    /* P3: Q3 (m4-7 x n2-3) */                                                \
    readB(0, 2);                                                              \
    stageA(1, 1, t1);                                                         \
    BAR(); LGKM0();                                                           \
    domfma(4, 2);                                                             \
    BAR();                                                                    \
    /* P4: Q2 (m0-3 x n2-3) + counted vmcnt */                                \
    readA(0, 0);                                                              \
    if (pf) stageB(0, 0, t2);                                                 \
    BAR(); LGKM0();                                                           \
    domfma(0, 2);                                                             \
    if (pf) { VMCNT2(); } else { VMCNT0(); }                                  \
    BAR();                                                                    \
    /* P5: buf1 Q0 */                                                         \
    readA(1, 0); readB(1, 0);                                                 \
    if (pf) stageB(0, 1, t2);                                                 \
    BAR(); LGKM0();                                                           \
    domfma(0, 0);                                                             \
    BAR();                                                                    \
    /* P6: Q1 */                                                              \
    readA(1, 4);                                                              \
    if (pf) stageA(0, 0, t2);                                                 \
    BAR(); LGKM0();                                                           \
    domfma(4, 0);                                                             \
    BAR();                                                                    \
    /* P7: Q3 */                                                              \
    readB(1, 2);                                                              \
    if (pf) stageA(0, 1, t2);                                                 \
    BAR(); LGKM0();                                                           \
    domfma(4, 2);                                                             \
    BAR();                                                                    \
    /* P8: Q2 + counted vmcnt */                                              \
    readA(1, 0);                                                              \
    if (pf) stageB(1, 0, t3);                                                 \
    BAR(); LGKM0();                                                           \
    domfma(0, 2);                                                             \
    if (pf) { VMCNT2(); } else { VMCNT0(); }                                  \
    BAR();                                                                    \
  }

// ---------------- fused QKV GEMM: 256x256, 8-phase ----------------
__global__ __launch_bounds__(512, 1)
void qkv_gemm(const u16* __restrict__ X, const u16* __restrict__ W,
              u16* __restrict__ Qo, u16* __restrict__ Ko, u16* __restrict__ VTo) {
  __shared__ __align__(16) u16 At[2][2][128 * 64];
  __shared__ __align__(16) u16 Bt[2][2][128 * 64];
  const int tid = threadIdx.x;
  const int w = tid >> 6, lane = tid & 63;
  const int g = lane >> 4, c16 = lane & 15;
  const int wr = w >> 2, wc = w & 3;
  const int M0 = blockIdx.x * 256;
  const int N0 = blockIdx.y * 256;
  const u16* Abase = X + (size_t)M0 * 1024;
  const u16* Bbase = W + (size_t)N0 * 1024;

  f32x4 acc[8][4] = {};
  GEMM8_CORE(Abase, Bbase);

  const int which = N0 >> 10;                  // 0=Q, 1=K, 2=V
  const int colbase = N0 & 1023;
#pragma unroll
  for (int m = 0; m < 8; ++m) {
#pragma unroll
    for (int n = 0; n < 4; ++n) {
#pragma unroll
      for (int r = 0; r < 4; ++r) {
        int gm  = M0 + wr * 128 + m * 16 + 4 * g + r;
        int col = colbase + wc * 64 + n * 16 + c16;
        u16 hv = f2bf(acc[m][n][r]);
        if (which == 0) {
          Qo[(size_t)gm * 1024 + col] = hv;
        } else if (which == 1) {
          Ko[(size_t)gm * 1024 + col] = hv;
        } else {
          int b = gm >> 12, s2 = gm & 4095;
          VTo[((size_t)((b << 10) + col)) * 4096 + s2] = hv;
        }
      }
    }
  }
}

// ---------------- S-GEMM + exp: 256x256 causal tiles, 8-phase ----------------
__global__ __launch_bounds__(512, 1)
void sgemm_exp(const u16* __restrict__ Q, const u16* __restrict__ K,
               u16* __restrict__ Spack, float* __restrict__ lpart) {
  __shared__ __align__(16) u16 At[2][2][128 * 64];
  __shared__ __align__(16) u16 Bt[2][2][128 * 64];
  __shared__ float lsum[256][4];
  const int tid = threadIdx.x;
  const int w = tid >> 6, lane = tid & 63;
  const int g = lane >> 4, c16 = lane & 15;
  const int wr = w >> 2, wc = w & 3;
  const int b = blockIdx.y;

  int L = blockIdx.x, qt = 0;                  // triangular decode
  while ((qt + 1) * (qt + 2) / 2 <= L) ++qt;
  const int kt = L - qt * (qt + 1) / 2;

  const u16* Abase = Q + (size_t)b * 4096 * 1024 + (size_t)qt * 256 * 1024;
  const u16* Bbase = K + (size_t)b * 4096 * 1024 + (size_t)kt * 256 * 1024;

  f32x4 acc[8][4] = {};
  GEMM8_CORE(Abase, Bbase);

  // epilogue: exp + mask, store into 128-tile packed layout, row-sum partials.
  const int qt128 = 2 * qt + wr;
  const int kt128 = 2 * kt + (wc >> 1);
  const bool exists = (kt128 <= qt128);
  u16* Sb = Spack + (((size_t)b * 528 + (size_t)(qt128 * (qt128 + 1)) / 2 + kt128) << 14);
  const int q0 = qt * 256, k0g = kt * 256;
  float psum[8][4];
#pragma unroll
  for (int m = 0; m < 8; ++m)
#pragma unroll
    for (int r = 0; r < 4; ++r) psum[m][r] = 0.f;
#pragma unroll
  for (int m = 0; m < 8; ++m) {
#pragma unroll
    for (int n = 0; n < 4; ++n) {
#pragma unroll
      for (int r = 0; r < 4; ++r) {
        int rl = wr * 128 + m * 16 + 4 * g + r;
        int cl = wc * 64 + n * 16 + c16;
        float s = acc[m][n][r] * 0.03125f;     // 1/sqrt(1024)
        float p = (k0g + cl <= q0 + rl) ? __expf(s) : 0.f;
        u16 pb = f2bf(p);
        if (exists) Sb[(rl & 127) * 128 + (cl & 127)] = pb;
        psum[m][r] += bf2f(pb);
      }
    }
  }
#pragma unroll
  for (int m = 0; m < 8; ++m)
#pragma unroll
    for (int r = 0; r < 4; ++r) {
      float v = psum[m][r];
      v += __shfl_xor(v, 1, 64);
      v += __shfl_xor(v, 2, 64);
      v += __shfl_xor(v, 4, 64);
      v += __shfl_xor(v, 8, 64);
      psum[m][r] = v;
    }
  if (c16 == 0) {
#pragma unroll
    for (int m = 0; m < 8; ++m)
#pragma unroll
      for (int r = 0; r < 4; ++r)
        lsum[wr * 128 + m * 16 + 4 * g + r][wc] = psum[m][r];
  }
  __syncthreads();
  if (tid < 256) {
    float v = lsum[tid][0] + lsum[tid][1] + lsum[tid][2] + lsum[tid][3];
    lpart[((size_t)b * 4096 + q0 + tid) * 16 + kt] = v;
  }
}

// ---------------- l reduction -> 1/l ----------------
__global__ __launch_bounds__(256)
void lreduce(const float* __restrict__ lpart, float* __restrict__ linv) {
  int row = blockIdx.x * 256 + threadIdx.x;    // 0..16383
  int nt  = ((row & 4095) >> 8) + 1;           // valid 256-col partials
  const float* p = lpart + (size_t)row * 16;
  float s = 0.f;
  for (int i = 0; i < nt; ++i) s += p[i];
  linv[row] = 1.f / s;
}

// ---------------- PV GEMM: 256x128 paired q-tiles (R5 proven) ----------------
__global__ __launch_bounds__(512)
void pv_gemm(const u16* __restrict__ Spack, const u16* __restrict__ VT,
             const u16* __restrict__ ztile, const float* __restrict__ linv,
             float* __restrict__ Out) {
  __shared__ __align__(16) u16 At[2][256 * 64];
  __shared__ __align__(16) u16 Bt[2][128 * 64];
  const int tid = threadIdx.x;
  const int w = tid >> 6, lane = tid & 63;
  const int g = lane >> 4, c16 = lane & 15;
  const int wm = w >> 1, wn = w & 1;           // wave out: rows wm*64, cols wn*64
  const int pp = blockIdx.x;
  const int d0 = blockIdx.y;
  const int b  = blockIdx.z;

  const u16* Sp_b = Spack + (size_t)b * 528 * 16384;
  const u16* VTb  = VT + (size_t)b * 1024 * 4096;
  float* Ob = Out + (size_t)b * 4096 * 1024;

  for (int pass = 0; pass < 2; ++pass) {
    const int QT = pass == 0 ? pp : 15 - pp;
    const int M0 = QT * 256;
    const int nsteps = (QT + 1) * 4;
    const int tLo = 2 * QT;
    const size_t triLo = (size_t)(tLo * (tLo + 1)) / 2;
    const size_t triHi = (size_t)((tLo + 1) * (tLo + 2)) / 2;

    f32x4 acc[4][4] = {};

    auto stage = [&](int s, int tt) {
      const int kv0 = tt * 64;
      const int kt128 = tt >> 1;
      const int koff = (tt & 1) * 64;
      const u16* baseLo = (kt128 <= tLo) ? Sp_b + ((triLo + kt128) << 14) : ztile;
      const u16* baseHi = Sp_b + ((triHi + kt128) << 14);
#pragma unroll
      for (int i = 0; i < 4; ++i) {
        int ci = i * 512 + tid;
        int r = ci >> 3;
        int c = (ci & 7) ^ (r & 7);
        const u16* base = (i < 2) ? baseLo : baseHi;
        gld_lds16(base + (size_t)(r & 127) * 128 + koff + c * 8, &At[s][ci * 8]);
      }
#pragma unroll
      for (int i = 0; i < 2; ++i) {
        int ci = i * 512 + tid;
        int r = ci >> 3;
        int c = (ci & 7) ^ (r & 7);
        gld_lds16(VTb + (size_t)(d0 * 128 + r) * 4096 + kv0 + c * 8, &Bt[s][ci * 8]);
      }
    };
    auto compute = [&](int s) {
#pragma unroll
      for (int dk = 0; dk < 2; ++dk) {
        bf16x8 af2[4], bf2[4];
#pragma unroll
        for (int m = 0; m < 4; ++m) {
          int row = wm * 64 + m * 16 + c16;
          int ch = dk * 4 + g;
          af2[m] = *(const bf16x8*)&At[s][row * 64 + ((ch ^ (row & 7)) * 8)];
        }
#pragma unroll
        for (int n = 0; n < 4; ++n) {
          int row = wn * 64 + n * 16 + c16;
          int ch = dk * 4 + g;
          bf2[n] = *(const bf16x8*)&Bt[s][row * 64 + ((ch ^ (row & 7)) * 8)];
        }
#pragma unroll
        for (int m = 0; m < 4; ++m)
#pragma unroll
          for (int n = 0; n < 4; ++n)
            acc[m][n] = mfma16(af2[m], bf2[n], acc[m][n]);
      }
    };

    stage(0, 0);
    __syncthreads();
    int cur = 0;
    for (int t = 0; t < nsteps; ++t) {
      if (t + 1 < nsteps) stage(cur ^ 1, t + 1);
      compute(cur);
      __syncthreads();
      cur ^= 1;
    }

    const float* lb = linv + (size_t)b * 4096 + M0;
#pragma unroll
    for (int m = 0; m < 4; ++m) {
#pragma unroll
      for (int r = 0; r < 4; ++r) {
        int rl = wm * 64 + m * 16 + 4 * g + r;
        float li = lb[rl];
#pragma unroll
        for (int n = 0; n < 4; ++n) {
          int dcol = d0 * 128 + wn * 64 + n * 16 + c16;
          Ob[(size_t)(M0 + rl) * 1024 + dcol] = acc[m][n][r] * li;
        }
      }
    }
  }
}

// ---------------- fallback attn (R1, proven 558us) ----------------
__global__ __launch_bounds__(512, 2)
void attn_kernel(const u16* __restrict__ Q, const u16* __restrict__ K,
                 const u16* __restrict__ VT, float* __restrict__ Out) {
  __shared__ u16 kv_lds[32 * 1024];
  __shared__ float s_part[4][32][33];
  __shared__ u16 p_lds[32 * 40];
  __shared__ float l_lds[32];

  const int tid = threadIdx.x;
  const int w = tid >> 6, lane = tid & 63;
  const int g = lane >> 4, c16 = lane & 15;
  const int b  = blockIdx.x & 3;
  const int qb = 127 - (blockIdx.x >> 2);
  const int qs = qb * 32;
  const int kh = w & 1, dq = w >> 1;

  const u16* Qb  = Q  + (size_t)b * 4096 * 1024;
  const u16* Kb  = K  + (size_t)b * 4096 * 1024;
  const u16* VTb = VT + (size_t)b * 1024 * 4096;

  bf16x8 qfrag[2][8];
#pragma unroll
  for (int qh = 0; qh < 2; ++qh)
#pragma unroll
    for (int dk = 0; dk < 8; ++dk)
      qfrag[qh][dk] = *(const bf16x8*)(Qb + (size_t)(qs + qh * 16 + c16) * 1024
                                       + dq * 256 + dk * 32 + g * 8);

  f32x4 oacc[2][8] = {};
  if (tid < 32) l_lds[tid] = 0.f;

  const int qrow_p = tid >> 4;
  const int kk     = tid & 15;
  const int gq     = qs + qrow_p;

  for (int j = 0; j <= qb; ++j) {
    const int kv0 = j * 32;
    __syncthreads();
    uint4 rk[8];
#pragma unroll
    for (int i = 0; i < 8; ++i) {
      int ci = i * 512 + tid;
      int r  = ci >> 7;
      int c  = (ci & 127) ^ (r & 7);
      rk[i] = *(const uint4*)(Kb + (size_t)(kv0 + r) * 1024 + c * 8);
    }
#pragma unroll
    for (int i = 0; i < 8; ++i)
      *(uint4*)&kv_lds[(size_t)(i * 512 + tid) * 8] = rk[i];
    __syncthreads();
    f32x4 sacc[2] = {};
#pragma unroll
    for (int dk = 0; dk < 8; ++dk) {
      int kvrow = kh * 16 + c16;
      int ch    = dq * 32 + dk * 4 + g;
      bf16x8 kf = *(const bf16x8*)&kv_lds[kvrow * 1024 + ((ch ^ (kvrow & 7)) * 8)];
      sacc[0] = mfma16(qfrag[0][dk], kf, sacc[0]);
      sacc[1] = mfma16(qfrag[1][dk], kf, sacc[1]);
    }
#pragma unroll
    for (int qh = 0; qh < 2; ++qh)
#pragma unroll
      for (int r = 0; r < 4; ++r)
        s_part[dq][qh * 16 + 4 * g + r][kh * 16 + c16] = sacc[qh][r];
    __syncthreads();
    uint4 rv[8];
#pragma unroll
    for (int i = 0; i < 8; ++i) {
      int ci = i * 512 + tid;
      int d  = ((ci >> 6) << 4) + (ci & 15);
      int c  = (ci >> 4) & 3;
      rv[i] = *(const uint4*)(VTb + (size_t)d * 4096 + kv0 + c * 8);
    }
    {
      float psum = 0.f;
#pragma unroll
      for (int h = 0; h < 2; ++h) {
        int kcol = kk + h * 16;
        float s = s_part[0][qrow_p][kcol] + s_part[1][qrow_p][kcol]
                + s_part[2][qrow_p][kcol] + s_part[3][qrow_p][kcol];
        s *= 0.03125f;
        float p = (kv0 + kcol <= gq) ? __expf(s) : 0.f;
        u16 pb = f2bf(p);
        p_lds[qrow_p * 40 + kcol] = pb;
        psum += bf2f(pb);
      }
#pragma unroll
      for (int off = 1; off < 16; off <<= 1)
        psum += __shfl_xor(psum, off, 64);
      if (kk == 0) l_lds[qrow_p] += psum;
    }
#pragma unroll
    for (int i = 0; i < 8; ++i)
      *(uint4*)&kv_lds[(size_t)(i * 512 + tid) * 8] = rv[i];
    __syncthreads();
    bf16x8 pa0 = *(const bf16x8*)&p_lds[(0  + c16) * 40 + g * 8];
    bf16x8 pa1 = *(const bf16x8*)&p_lds[(16 + c16) * 40 + g * 8];
#pragma unroll
    for (int f = 0; f < 8; ++f) {
      int dcol = w * 128 + f * 16 + c16;
      int pos  = (dcol >> 4) * 64 + g * 16 + (dcol & 15);
      bf16x8 vf = *(const bf16x8*)&kv_lds[(size_t)pos * 8];
      oacc[0][f] = mfma16(pa0, vf, oacc[0][f]);
      oacc[1][f] = mfma16(pa1, vf, oacc[1][f]);
    }
  }

  float* Ob = Out + (size_t)b * 4096 * 1024;
#pragma unroll
  for (int qh = 0; qh < 2; ++qh) {
#pragma unroll
    for (int r = 0; r < 4; ++r) {
      int ql = qh * 16 + 4 * g + r;
      float linvv = 1.f / l_lds[ql];
#pragma unroll
      for (int f = 0; f < 8; ++f)
        Ob[(size_t)(qs + ql) * 1024 + w * 128 + f * 16 + c16] = oacc[qh][f][r] * linvv;
    }
  }
}

extern "C" void kernel_launch(void* const* d_in, const int* in_sizes, int n_in,
                              void* d_out, int out_size, void* d_ws, size_t ws_size,
                              hipStream_t stream) {
  const float* x  = (const float*)d_in[0];
  const float* Wq = (const float*)d_in[1];
  const float* Wk = (const float*)d_in[2];
  const float* Wv = (const float*)d_in[3];
  float* out = (float*)d_out;

  u16* ws    = (u16*)d_ws;
  u16* wWqkv = ws;                                   // 3M elems
  u16* wX    = wWqkv + (size_t)3 * 1024 * 1024;      // dead after qkv -> zero tile
  u16* wQ    = wX + (size_t)16384 * 1024;
  u16* wK    = wQ + (size_t)16384 * 1024;
  u16* wVT   = wK + (size_t)16384 * 1024;            // [4][1024][4096]
  u16* wSp   = wVT + (size_t)16384 * 1024;           // packed 128-tile triangle
  float* lpart = (float*)(ws + (size_t)104857600);   // 16384*16 f32 (1MB)
  float* linv  = (float*)(ws + (size_t)105906176);   // 16384 f32

  cast_f32_bf16<<<dim3(8192), 256, 0, stream>>>(x, wX, 16777216 / 8);
  cast_f32_bf16<<<dim3(512), 256, 0, stream>>>(Wq, wWqkv,                 1048576 / 8);
  cast_f32_bf16<<<dim3(512), 256, 0, stream>>>(Wk, wWqkv + 1048576,       1048576 / 8);
  cast_f32_bf16<<<dim3(512), 256, 0, stream>>>(Wv, wWqkv + 2 * 1048576,   1048576 / 8);

  qkv_gemm<<<dim3(64, 12), 512, 0, stream>>>(wX, wWqkv, wQ, wK, wVT);

  if (ws_size >= (size_t)211877888) {
    hipMemsetAsync(wX, 0, 32768, stream);            // zero tile for absent causal tiles
    sgemm_exp<<<dim3(136, 4), 512, 0, stream>>>(wQ, wK, wSp, lpart);
    lreduce<<<dim3(64), 256, 0, stream>>>(lpart, linv);
    pv_gemm<<<dim3(8, 8, 4), 512, 0, stream>>>(wSp, wVT, wX, linv, out);
  } else {
    attn_kernel<<<dim3(512), 512, 0, stream>>>(wQ, wK, wVT, out);
  }
}

// Round 9
// 373.392 us; speedup vs baseline: 1.2381x; 1.0678x over previous
//
#include <hip/hip_runtime.h>

// CausalAttention: B=4, S=4096, D=1024 (single head, head_dim=1024)
// v9: fused-cast -> QKV GEMM (VT, XCD-striped) -> S-GEMM+exp (causal triangle,
//     XCD-chunked) -> PV GEMM (fused l-reduce, scale 1/l). No-max softmax
//     (validated R1). All GEMMs: R5's proven 256-tile dbuf 2-phase structure
//     (stage-next -> compute -> syncthreads), conflict-free chunk-XOR LDS,
//     global_load_lds width=16.
// ws (u16 elems): Wqkv[3M] | X[16M, zero-tile after qkv] | Q[16M] | K[16M] |
//   VT[16M] | Spack[34.6M packed 128-tiles] | lpart[16384*16 f32]

typedef unsigned short u16;
typedef unsigned int u32;
typedef __attribute__((ext_vector_type(8))) short bf16x8;
typedef __attribute__((ext_vector_type(4))) float f32x4;
typedef __attribute__((ext_vector_type(8))) unsigned short u16x8;

__device__ __forceinline__ u16 f2bf(float f) {
  union { float f; unsigned u; } v; v.f = f;
  unsigned r = v.u + 0x7FFFu + ((v.u >> 16) & 1u);  // RNE
  return (u16)(r >> 16);
}
__device__ __forceinline__ float bf2f(u16 h) {
  union { unsigned u; float f; } v; v.u = ((unsigned)h) << 16;
  return v.f;
}
__device__ __forceinline__ f32x4 mfma16(bf16x8 a, bf16x8 b, f32x4 c) {
  return __builtin_amdgcn_mfma_f32_16x16x32_bf16(a, b, c, 0, 0, 0);
}
__device__ __forceinline__ void gld_lds16(const u16* g, u16* l) {
  __builtin_amdgcn_global_load_lds(
      (const __attribute__((address_space(1))) u32*)g,
      (__attribute__((address_space(3))) u32*)l, 16, 0, 0);
}

// ---------------- fused cast f32 -> bf16 (x, Wq, Wk, Wv in one launch) ----------------
// chunk ids: [0, 2097152) -> x, then 131072 each for Wq, Wk, Wv.
__global__ __launch_bounds__(256)
void cast_all(const float* __restrict__ x, const float* __restrict__ Wq,
              const float* __restrict__ Wk, const float* __restrict__ Wv,
              u16* __restrict__ wX, u16* __restrict__ wWqkv) {
  int i = blockIdx.x * 256 + threadIdx.x;
  const float* src; u16* dst; int j;
  if (i < 2097152)        { src = x;  dst = wX;                j = i; }
  else if (i < 2228224)   { src = Wq; dst = wWqkv;             j = i - 2097152; }
  else if (i < 2359296)   { src = Wk; dst = wWqkv + 1048576;   j = i - 2228224; }
  else if (i < 2490368)   { src = Wv; dst = wWqkv + 2097152;   j = i - 2359296; }
  else return;
  const float4* s4 = (const float4*)src;
  float4 a = s4[2*j], b = s4[2*j+1];
  u16x8 o;
  o[0]=f2bf(a.x); o[1]=f2bf(a.y); o[2]=f2bf(a.z); o[3]=f2bf(a.w);
  o[4]=f2bf(b.x); o[5]=f2bf(b.y); o[6]=f2bf(b.z); o[7]=f2bf(b.w);
  ((u16x8*)dst)[j] = o;
}

// ---------------- fused QKV GEMM: 256x256 dbuf 2-phase, XCD-striped ----------------
// 1D grid of 768. XCD k (= lid&7) owns M-tiles [8k, 8k+8) for all N-tiles:
// its X working set = 8*512KB = 4MB = exactly one XCD's private L2.
__global__ __launch_bounds__(512)
void qkv_gemm(const u16* __restrict__ X, const u16* __restrict__ W,
              u16* __restrict__ Qo, u16* __restrict__ Ko, u16* __restrict__ VTo) {
  __shared__ __align__(16) u16 At[2][256 * 64];
  __shared__ __align__(16) u16 Bt[2][256 * 64];
  const int tid = threadIdx.x;
  const int w = tid >> 6, lane = tid & 63;
  const int g = lane >> 4, c16 = lane & 15;
  const int wr = w >> 2, wc = w & 3;           // wave tile: rows wr*128, cols wc*64
  const int lid = blockIdx.x;
  const int xcd = lid & 7, gg = lid >> 3;      // gg in [0,96)
  const int M0 = ((xcd << 3) | (gg & 7)) * 256;
  const int N0 = (gg >> 3) * 256;

  f32x4 acc[8][4] = {};

  auto stage = [&](int s, int k0) {
#pragma unroll
    for (int i = 0; i < 4; ++i) {
      int ci = i * 512 + tid;                  // 2048 chunks (256 rows x 8)
      int r = ci >> 3;
      int c = (ci & 7) ^ (r & 7);
      gld_lds16(X + (size_t)(M0 + r) * 1024 + k0 + c * 8, &At[s][ci * 8]);
    }
#pragma unroll
    for (int i = 0; i < 4; ++i) {
      int ci = i * 512 + tid;
      int r = ci >> 3;
      int c = (ci & 7) ^ (r & 7);
      gld_lds16(W + (size_t)(N0 + r) * 1024 + k0 + c * 8, &Bt[s][ci * 8]);
    }
  };
  auto compute = [&](int s) {
#pragma unroll
    for (int dk = 0; dk < 2; ++dk) {
      bf16x8 af[8], bfr[4];
#pragma unroll
      for (int m = 0; m < 8; ++m) {
        int row = wr * 128 + m * 16 + c16;
        int ch = dk * 4 + g;
        af[m] = *(const bf16x8*)&At[s][row * 64 + ((ch ^ (row & 7)) * 8)];
      }
#pragma unroll
      for (int n = 0; n < 4; ++n) {
        int row = wc * 64 + n * 16 + c16;
        int ch = dk * 4 + g;
        bfr[n] = *(const bf16x8*)&Bt[s][row * 64 + ((ch ^ (row & 7)) * 8)];
      }
#pragma unroll
      for (int m = 0; m < 8; ++m)
#pragma unroll
        for (int n = 0; n < 4; ++n)
          acc[m][n] = mfma16(af[m], bfr[n], acc[m][n]);
    }
  };

  stage(0, 0);
  __syncthreads();
  int cur = 0;
  for (int t = 0; t < 16; ++t) {
    if (t < 15) stage(cur ^ 1, (t + 1) * 64);
    compute(cur);
    __syncthreads();                           // drains staged loads (overlapped w/ MFMA)
    cur ^= 1;
  }

  const int which = N0 >> 10;                  // 0=Q, 1=K, 2=V
  const int colbase = N0 & 1023;
#pragma unroll
  for (int m = 0; m < 8; ++m) {
#pragma unroll
    for (int n = 0; n < 4; ++n) {
#pragma unroll
      for (int r = 0; r < 4; ++r) {
        int gm  = M0 + wr * 128 + m * 16 + 4 * g + r;
        int col = colbase + wc * 64 + n * 16 + c16;
        u16 hv = f2bf(acc[m][n][r]);
        if (which == 0) {
          Qo[(size_t)gm * 1024 + col] = hv;
        } else if (which == 1) {
          Ko[(size_t)gm * 1024 + col] = hv;
        } else {
          int b = gm >> 12, s = gm & 4095;
          VTo[((size_t)((b << 10) + col)) * 4096 + s] = hv;
        }
      }
    }
  }
}

// ---------------- S-GEMM + exp: 256x256 causal tiles, dbuf, XCD-chunked ----------------
// grid.x = 136 (17 per XCD, contiguous triangle cells -> Q/K panel L2 reuse).
__global__ __launch_bounds__(512)
void sgemm_exp(const u16* __restrict__ Q, const u16* __restrict__ K,
               u16* __restrict__ Spack, float* __restrict__ lpart) {
  __shared__ __align__(16) u16 At[2][256 * 64];
  __shared__ __align__(16) u16 Bt[2][256 * 64];
  __shared__ float lsum[256][4];
  const int tid = threadIdx.x;
  const int w = tid >> 6, lane = tid & 63;
  const int g = lane >> 4, c16 = lane & 15;
  const int wr = w >> 2, wc = w & 3;
  const int b = blockIdx.y;

  int L = (blockIdx.x & 7) * 17 + (blockIdx.x >> 3);   // bijective XCD chunking (136=17*8)
  int qt = 0;
  while ((qt + 1) * (qt + 2) / 2 <= L) ++qt;
  const int kt = L - qt * (qt + 1) / 2;

  const u16* Qb = Q + (size_t)b * 4096 * 1024 + (size_t)qt * 256 * 1024;
  const u16* Kb = K + (size_t)b * 4096 * 1024 + (size_t)kt * 256 * 1024;

  f32x4 acc[8][4] = {};

  auto stage = [&](int s, int k0) {
#pragma unroll
    for (int i = 0; i < 4; ++i) {
      int ci = i * 512 + tid;
      int r = ci >> 3;
      int c = (ci & 7) ^ (r & 7);
      gld_lds16(Qb + (size_t)r * 1024 + k0 + c * 8, &At[s][ci * 8]);
    }
#pragma unroll
    for (int i = 0; i < 4; ++i) {
      int ci = i * 512 + tid;
      int r = ci >> 3;
      int c = (ci & 7) ^ (r & 7);
      gld_lds16(Kb + (size_t)r * 1024 + k0 + c * 8, &Bt[s][ci * 8]);
    }
  };
  auto compute = [&](int s) {
#pragma unroll
    for (int dk = 0; dk < 2; ++dk) {
      bf16x8 af[8], bfr[4];
#pragma unroll
      for (int m = 0; m < 8; ++m) {
        int row = wr * 128 + m * 16 + c16;
        int ch = dk * 4 + g;
        af[m] = *(const bf16x8*)&At[s][row * 64 + ((ch ^ (row & 7)) * 8)];
      }
#pragma unroll
      for (int n = 0; n < 4; ++n) {
        int row = wc * 64 + n * 16 + c16;
        int ch = dk * 4 + g;
        bfr[n] = *(const bf16x8*)&Bt[s][row * 64 + ((ch ^ (row & 7)) * 8)];
      }
#pragma unroll
      for (int m = 0; m < 8; ++m)
#pragma unroll
        for (int n = 0; n < 4; ++n)
          acc[m][n] = mfma16(af[m], bfr[n], acc[m][n]);
    }
  };

  stage(0, 0);
  __syncthreads();
  int cur = 0;
  for (int t = 0; t < 16; ++t) {
    if (t < 15) stage(cur ^ 1, (t + 1) * 64);
    compute(cur);
    __syncthreads();
    cur ^= 1;
  }

  // epilogue: exp + mask, store into 128-tile packed layout, row-sum partials.
  const int qt128 = 2 * qt + wr;               // uniform per thread
  const int kt128 = 2 * kt + (wc >> 1);        // uniform per thread
  const bool exists = (kt128 <= qt128);
  u16* Sb = Spack + (((size_t)b * 528 + (size_t)(qt128 * (qt128 + 1)) / 2 + kt128) << 14);
  const int q0 = qt * 256, k0g = kt * 256;
  float psum[8][4];
#pragma unroll
  for (int m = 0; m < 8; ++m)
#pragma unroll
    for (int r = 0; r < 4; ++r) psum[m][r] = 0.f;
#pragma unroll
  for (int m = 0; m < 8; ++m) {
#pragma unroll
    for (int n = 0; n < 4; ++n) {
#pragma unroll
      for (int r = 0; r < 4; ++r) {
        int rl = wr * 128 + m * 16 + 4 * g + r;
        int cl = wc * 64 + n * 16 + c16;
        float s = acc[m][n][r] * 0.03125f;     // 1/sqrt(1024)
        float p = (k0g + cl <= q0 + rl) ? __expf(s) : 0.f;
        u16 pb = f2bf(p);
        if (exists) Sb[(rl & 127) * 128 + (cl & 127)] = pb;
        psum[m][r] += bf2f(pb);
      }
    }
  }
#pragma unroll
  for (int m = 0; m < 8; ++m)
#pragma unroll
    for (int r = 0; r < 4; ++r) {
      float v = psum[m][r];
      v += __shfl_xor(v, 1, 64);
      v += __shfl_xor(v, 2, 64);
      v += __shfl_xor(v, 4, 64);
      v += __shfl_xor(v, 8, 64);
      psum[m][r] = v;
    }
  if (c16 == 0) {
#pragma unroll
    for (int m = 0; m < 8; ++m)
#pragma unroll
      for (int r = 0; r < 4; ++r)
        lsum[wr * 128 + m * 16 + 4 * g + r][wc] = psum[m][r];
  }
  __syncthreads();
  if (tid < 256) {
    float v = lsum[tid][0] + lsum[tid][1] + lsum[tid][2] + lsum[tid][3];
    lpart[((size_t)b * 4096 + q0 + tid) * 16 + kt] = v;
  }
}

// ---------------- PV GEMM: 256x128 paired q-tiles, fused l-reduce ----------------
// grid = (8 pairs, 8 d-tiles, 4 batches) = 256 = 1/CU, uniform 68 K-steps.
// l-reduce computed per block into LDS before the K-loop (overlaps prologue).
__global__ __launch_bounds__(512)
void pv_gemm(const u16* __restrict__ Spack, const u16* __restrict__ VT,
             const u16* __restrict__ ztile, const float* __restrict__ lpart,
             float* __restrict__ Out) {
  __shared__ __align__(16) u16 At[2][256 * 64];
  __shared__ __align__(16) u16 Bt[2][128 * 64];
  __shared__ float linv_lds[512];              // [pass][256]
  const int tid = threadIdx.x;
  const int w = tid >> 6, lane = tid & 63;
  const int g = lane >> 4, c16 = lane & 15;
  const int wm = w >> 1, wn = w & 1;           // wave tile: rows wm*64, cols wn*64
  const int pp = blockIdx.x;
  const int d0 = blockIdx.y;
  const int b  = blockIdx.z;

  const u16* Sp_b = Spack + (size_t)b * 528 * 16384;
  const u16* VTb  = VT + (size_t)b * 1024 * 4096;
  float* Ob = Out + (size_t)b * 4096 * 1024;

  // fused l-reduce: thread tid handles one of the block's 512 output rows.
  {
    const int QTr = (tid < 256) ? pp : (15 - pp);
    const int row = QTr * 256 + (tid & 255);   // row within batch
    const int nt  = QTr + 1;                   // valid 256-col partials
    const float* p = lpart + ((size_t)b * 4096 + row) * 16;
    float s = 0.f;
    for (int i = 0; i < nt; ++i) s += p[i];
    linv_lds[tid] = 1.f / s;
  }

  for (int pass = 0; pass < 2; ++pass) {
    const int QT = pass == 0 ? pp : 15 - pp;
    const int M0 = QT * 256;
    const int nsteps = (QT + 1) * 4;
    const int tLo = 2 * QT;
    const size_t triLo = (size_t)(tLo * (tLo + 1)) / 2;
    const size_t triHi = (size_t)((tLo + 1) * (tLo + 2)) / 2;

    f32x4 acc[4][4] = {};

    auto stage = [&](int s, int tt) {
      const int kv0 = tt * 64;
      const int kt128 = tt >> 1;
      const int koff = (tt & 1) * 64;
      const u16* baseLo = (kt128 <= tLo) ? Sp_b + ((triLo + kt128) << 14) : ztile;
      const u16* baseHi = Sp_b + ((triHi + kt128) << 14);
#pragma unroll
      for (int i = 0; i < 4; ++i) {
        int ci = i * 512 + tid;
        int r = ci >> 3;
        int c = (ci & 7) ^ (r & 7);
        const u16* base = (i < 2) ? baseLo : baseHi;
        gld_lds16(base + (size_t)(r & 127) * 128 + koff + c * 8, &At[s][ci * 8]);
      }
#pragma unroll
      for (int i = 0; i < 2; ++i) {
        int ci = i * 512 + tid;
        int r = ci >> 3;
        int c = (ci & 7) ^ (r & 7);
        gld_lds16(VTb + (size_t)(d0 * 128 + r) * 4096 + kv0 + c * 8, &Bt[s][ci * 8]);
      }
    };
    auto compute = [&](int s) {
#pragma unroll
      for (int dk = 0; dk < 2; ++dk) {
        bf16x8 af[4], bfr[4];
#pragma unroll
        for (int m = 0; m < 4; ++m) {
          int row = wm * 64 + m * 16 + c16;
          int ch = dk * 4 + g;
          af[m] = *(const bf16x8*)&At[s][row * 64 + ((ch ^ (row & 7)) * 8)];
        }
#pragma unroll
        for (int n = 0; n < 4; ++n) {
          int row = wn * 64 + n * 16 + c16;
          int ch = dk * 4 + g;
          bfr[n] = *(const bf16x8*)&Bt[s][row * 64 + ((ch ^ (row & 7)) * 8)];
        }
#pragma unroll
        for (int m = 0; m < 4; ++m)
#pragma unroll
          for (int n = 0; n < 4; ++n)
            acc[m][n] = mfma16(af[m], bfr[n], acc[m][n]);
      }
    };

    stage(0, 0);
    __syncthreads();
    int cur = 0;
    for (int t = 0; t < nsteps; ++t) {
      if (t + 1 < nsteps) stage(cur ^ 1, t + 1);
      compute(cur);
      __syncthreads();
      cur ^= 1;
    }

    const float* lb = linv_lds + pass * 256;
#pragma unroll
    for (int m = 0; m < 4; ++m) {
#pragma unroll
      for (int r = 0; r < 4; ++r) {
        int rl = wm * 64 + m * 16 + 4 * g + r;
        float li = lb[rl];
#pragma unroll
        for (int n = 0; n < 4; ++n) {
          int dcol = d0 * 128 + wn * 64 + n * 16 + c16;
          Ob[(size_t)(M0 + rl) * 1024 + dcol] = acc[m][n][r] * li;
        }
      }
    }
  }
}

// ---------------- fallback attn (R1, proven 558us) ----------------
__global__ __launch_bounds__(512, 2)
void attn_kernel(const u16* __restrict__ Q, const u16* __restrict__ K,
                 const u16* __restrict__ VT, float* __restrict__ Out) {
  __shared__ u16 kv_lds[32 * 1024];
  __shared__ float s_part[4][32][33];
  __shared__ u16 p_lds[32 * 40];
  __shared__ float l_lds[32];

  const int tid = threadIdx.x;
  const int w = tid >> 6, lane = tid & 63;
  const int g = lane >> 4, c16 = lane & 15;
  const int b  = blockIdx.x & 3;
  const int qb = 127 - (blockIdx.x >> 2);
  const int qs = qb * 32;
  const int kh = w & 1, dq = w >> 1;

  const u16* Qb  = Q  + (size_t)b * 4096 * 1024;
  const u16* Kb  = K  + (size_t)b * 4096 * 1024;
  const u16* VTb = VT + (size_t)b * 1024 * 4096;

  bf16x8 qfrag[2][8];
#pragma unroll
  for (int qh = 0; qh < 2; ++qh)
#pragma unroll
    for (int dk = 0; dk < 8; ++dk)
      qfrag[qh][dk] = *(const bf16x8*)(Qb + (size_t)(qs + qh * 16 + c16) * 1024
                                       + dq * 256 + dk * 32 + g * 8);

  f32x4 oacc[2][8] = {};
  if (tid < 32) l_lds[tid] = 0.f;

  const int qrow_p = tid >> 4;
  const int kk     = tid & 15;
  const int gq     = qs + qrow_p;

  for (int j = 0; j <= qb; ++j) {
    const int kv0 = j * 32;
    __syncthreads();
    uint4 rk[8];
#pragma unroll
    for (int i = 0; i < 8; ++i) {
      int ci = i * 512 + tid;
      int r  = ci >> 7;
      int c  = (ci & 127) ^ (r & 7);
      rk[i] = *(const uint4*)(Kb + (size_t)(kv0 + r) * 1024 + c * 8);
    }
#pragma unroll
    for (int i = 0; i < 8; ++i)
      *(uint4*)&kv_lds[(size_t)(i * 512 + tid) * 8] = rk[i];
    __syncthreads();
    f32x4 sacc[2] = {};
#pragma unroll
    for (int dk = 0; dk < 8; ++dk) {
      int kvrow = kh * 16 + c16;
      int ch    = dq * 32 + dk * 4 + g;
      bf16x8 kf = *(const bf16x8*)&kv_lds[kvrow * 1024 + ((ch ^ (kvrow & 7)) * 8)];
      sacc[0] = mfma16(qfrag[0][dk], kf, sacc[0]);
      sacc[1] = mfma16(qfrag[1][dk], kf, sacc[1]);
    }
#pragma unroll
    for (int qh = 0; qh < 2; ++qh)
#pragma unroll
      for (int r = 0; r < 4; ++r)
        s_part[dq][qh * 16 + 4 * g + r][kh * 16 + c16] = sacc[qh][r];
    __syncthreads();
    uint4 rv[8];
#pragma unroll
    for (int i = 0; i < 8; ++i) {
      int ci = i * 512 + tid;
      int d  = ((ci >> 6) << 4) + (ci & 15);
      int c  = (ci >> 4) & 3;
      rv[i] = *(const uint4*)(VTb + (size_t)d * 4096 + kv0 + c * 8);
    }
    {
      float psum = 0.f;
#pragma unroll
      for (int h = 0; h < 2; ++h) {
        int kcol = kk + h * 16;
        float s = s_part[0][qrow_p][kcol] + s_part[1][qrow_p][kcol]
                + s_part[2][qrow_p][kcol] + s_part[3][qrow_p][kcol];
        s *= 0.03125f;
        float p = (kv0 + kcol <= gq) ? __expf(s) : 0.f;
        u16 pb = f2bf(p);
        p_lds[qrow_p * 40 + kcol] = pb;
        psum += bf2f(pb);
      }
#pragma unroll
      for (int off = 1; off < 16; off <<= 1)
        psum += __shfl_xor(psum, off, 64);
      if (kk == 0) l_lds[qrow_p] += psum;
    }
#pragma unroll
    for (int i = 0; i < 8; ++i)
      *(uint4*)&kv_lds[(size_t)(i * 512 + tid) * 8] = rv[i];
    __syncthreads();
    bf16x8 pa0 = *(const bf16x8*)&p_lds[(0  + c16) * 40 + g * 8];
    bf16x8 pa1 = *(const bf16x8*)&p_lds[(16 + c16) * 40 + g * 8];
#pragma unroll
    for (int f = 0; f < 8; ++f) {
      int dcol = w * 128 + f * 16 + c16;
      int pos  = (dcol >> 4) * 64 + g * 16 + (dcol & 15);
      bf16x8 vf = *(const bf16x8*)&kv_lds[(size_t)pos * 8];
      oacc[0][f] = mfma16(pa0, vf, oacc[0][f]);
      oacc[1][f] = mfma16(pa1, vf, oacc[1][f]);
    }
  }

  float* Ob = Out + (size_t)b * 4096 * 1024;
#pragma unroll
  for (int qh = 0; qh < 2; ++qh) {
#pragma unroll
    for (int r = 0; r < 4; ++r) {
      int ql = qh * 16 + 4 * g + r;
      float linvv = 1.f / l_lds[ql];
#pragma unroll
      for (int f = 0; f < 8; ++f)
        Ob[(size_t)(qs + ql) * 1024 + w * 128 + f * 16 + c16] = oacc[qh][f][r] * linvv;
    }
  }
}

extern "C" void kernel_launch(void* const* d_in, const int* in_sizes, int n_in,
                              void* d_out, int out_size, void* d_ws, size_t ws_size,
                              hipStream_t stream) {
  const float* x  = (const float*)d_in[0];
  const float* Wq = (const float*)d_in[1];
  const float* Wk = (const float*)d_in[2];
  const float* Wv = (const float*)d_in[3];
  float* out = (float*)d_out;

  u16* ws    = (u16*)d_ws;
  u16* wWqkv = ws;                                   // 3M elems
  u16* wX    = wWqkv + (size_t)3 * 1024 * 1024;      // dead after qkv -> zero tile
  u16* wQ    = wX + (size_t)16384 * 1024;
  u16* wK    = wQ + (size_t)16384 * 1024;
  u16* wVT   = wK + (size_t)16384 * 1024;            // [4][1024][4096]
  u16* wSp   = wVT + (size_t)16384 * 1024;           // packed 128-tile triangle
  float* lpart = (float*)(ws + (size_t)104857600);   // 16384*16 f32 (1MB)

  cast_all<<<dim3(9728), 256, 0, stream>>>(x, Wq, Wk, Wv, wX, wWqkv);

  qkv_gemm<<<dim3(768), 512, 0, stream>>>(wX, wWqkv, wQ, wK, wVT);

  if (ws_size >= (size_t)211877888) {
    hipMemsetAsync(wX, 0, 32768, stream);            // zero tile for absent causal tiles
    sgemm_exp<<<dim3(136, 4), 512, 0, stream>>>(wQ, wK, wSp, lpart);
    pv_gemm<<<dim3(8, 8, 4), 512, 0, stream>>>(wSp, wVT, wX, lpart, out);
  } else {
    attn_kernel<<<dim3(512), 512, 0, stream>>>(wQ, wK, wVT, out);
  }
}

// Round 10
// 367.985 us; speedup vs baseline: 1.2563x; 1.0147x over previous
//
#include <hip/hip_runtime.h>

// CausalAttention: B=4, S=4096, D=1024 (single head, head_dim=1024)
// v10: fused-cast -> QKV GEMM (VT, XCD-striped) -> S-GEMM+exp (causal triangle,
//     XCD-chunked) -> PV GEMM (fused l-reduce). No-max softmax (validated R1).
// R10: qkv+sgemm on a corrected 8-phase counted-vmcnt schedule. Key fix vs R8:
// reads restructured so buf-A frees at P3 and buf-B at P4 (frags held in regs),
// stages mapped P3/P4 (buf0-next) and P7/P8 (buf1-next) -> stage-to-use
// distance 4-5 phases; vmcnt(8) at P4/P8 allows exactly the 2 newest stage
// pairs outstanding (T4: loads never drained mid-loop). R8 used vmcnt(2) =
// effectively drain-0 (the null). pv_gemm: R9 proven 2-phase + fused l-reduce.
// ws (u16 elems): Wqkv[3M] | X[16M, zero-tile after qkv] | Q[16M] | K[16M] |
//   VT[16M] | Spack[34.6M packed 128-tiles] | lpart[16384*16 f32]

typedef unsigned short u16;
typedef unsigned int u32;
typedef __attribute__((ext_vector_type(8))) short bf16x8;
typedef __attribute__((ext_vector_type(4))) float f32x4;
typedef __attribute__((ext_vector_type(8))) unsigned short u16x8;

__device__ __forceinline__ u16 f2bf(float f) {
  union { float f; unsigned u; } v; v.f = f;
  unsigned r = v.u + 0x7FFFu + ((v.u >> 16) & 1u);  // RNE
  return (u16)(r >> 16);
}
__device__ __forceinline__ float bf2f(u16 h) {
  union { unsigned u; float f; } v; v.u = ((unsigned)h) << 16;
  return v.f;
}
__device__ __forceinline__ f32x4 mfma16(bf16x8 a, bf16x8 b, f32x4 c) {
  return __builtin_amdgcn_mfma_f32_16x16x32_bf16(a, b, c, 0, 0, 0);
}
__device__ __forceinline__ void gld_lds16(const u16* g, u16* l) {
  __builtin_amdgcn_global_load_lds(
      (const __attribute__((address_space(1))) u32*)g,
      (__attribute__((address_space(3))) u32*)l, 16, 0, 0);
}
#define BAR() do { __builtin_amdgcn_s_barrier(); \
                   __builtin_amdgcn_sched_barrier(0); } while (0)
#define LGKM0() do { asm volatile("s_waitcnt lgkmcnt(0)" ::: "memory"); \
                     __builtin_amdgcn_sched_barrier(0); } while (0)
#define VMC(n) asm volatile("s_waitcnt vmcnt(" #n ")" ::: "memory")

// ---------------- fused cast f32 -> bf16 (x, Wq, Wk, Wv in one launch) ----------------
__global__ __launch_bounds__(256)
void cast_all(const float* __restrict__ x, const float* __restrict__ Wq,
              const float* __restrict__ Wk, const float* __restrict__ Wv,
              u16* __restrict__ wX, u16* __restrict__ wWqkv) {
  int i = blockIdx.x * 256 + threadIdx.x;
  const float* src; u16* dst; int j;
  if (i < 2097152)        { src = x;  dst = wX;                j = i; }
  else if (i < 2228224)   { src = Wq; dst = wWqkv;             j = i - 2097152; }
  else if (i < 2359296)   { src = Wk; dst = wWqkv + 1048576;   j = i - 2228224; }
  else if (i < 2490368)   { src = Wv; dst = wWqkv + 2097152;   j = i - 2359296; }
  else return;
  const float4* s4 = (const float4*)src;
  float4 a = s4[2*j], b = s4[2*j+1];
  u16x8 o;
  o[0]=f2bf(a.x); o[1]=f2bf(a.y); o[2]=f2bf(a.z); o[3]=f2bf(a.w);
  o[4]=f2bf(b.x); o[5]=f2bf(b.y); o[6]=f2bf(b.z); o[7]=f2bf(b.w);
  ((u16x8*)dst)[j] = o;
}

// 8-phase GEMM core (qkv / sgemm shared). 256x256 tile, 8 waves (wr 2M x wc 4N),
// BK=64, 2 K-tiles per iteration. Reads: P1 af[0-3]+bfr[0-1], P2 af[4-7],
// P3 bfr[2-3] (A LDS free after P2, B after P3). Stages: P3 A(t+2), P4 B(t+2),
// P7 A(t+3), P8 B(t+3). vmcnt(8) at P4/P8.
#define GEMM8_CORE(Abase, Bbase)                                              \
  auto stageA = [&](int bufi, int h, int t) {                                 \
    _Pragma("unroll")                                                         \
    for (int i = 0; i < 2; ++i) {                                             \
      int ci = i * 512 + tid;                                                 \
      int r  = ci >> 3;                                                       \
      int c  = (ci & 7) ^ (r & 7);                                            \
      gld_lds16(Abase + (size_t)(h * 128 + r) * 1024 + t * 64 + c * 8,        \
                &At[bufi][h][ci * 8]);                                        \
    }                                                                         \
  };                                                                          \
  auto stageB = [&](int bufi, int h, int t) {                                 \
    _Pragma("unroll")                                                         \
    for (int i = 0; i < 2; ++i) {                                             \
      int ci = i * 512 + tid;                                                 \
      int r  = ci >> 3;                                                       \
      int c  = (ci & 7) ^ (r & 7);                                            \
      gld_lds16(Bbase + (size_t)(h * 128 + r) * 1024 + t * 64 + c * 8,        \
                &Bt[bufi][h][ci * 8]);                                        \
    }                                                                         \
  };                                                                          \
  bf16x8 af[8][2], bfr[4][2];                                                 \
  auto readA = [&](int bufi, int mb) {                                        \
    _Pragma("unroll")                                                         \
    for (int m = 0; m < 4; ++m)                                               \
      _Pragma("unroll")                                                       \
      for (int dk = 0; dk < 2; ++dk) {                                        \
        int r  = (mb + m) * 16 + c16;                                         \
        int ch = dk * 4 + g;                                                  \
        af[mb + m][dk] =                                                      \
            *(const bf16x8*)&At[bufi][wr][r * 64 + ((ch ^ (r & 7)) * 8)];     \
      }                                                                       \
  };                                                                          \
  auto readB = [&](int bufi, int nb) {                                        \
    _Pragma("unroll")                                                         \
    for (int n = 0; n < 2; ++n)                                               \
      _Pragma("unroll")                                                       \
      for (int dk = 0; dk < 2; ++dk) {                                        \
        int r  = (wc & 1) * 64 + (nb + n) * 16 + c16;                         \
        int ch = dk * 4 + g;                                                  \
        bfr[nb + n][dk] =                                                     \
            *(const bf16x8*)&Bt[bufi][wc >> 1][r * 64 + ((ch ^ (r & 7)) * 8)];\
      }                                                                       \
  };                                                                          \
  auto domfma = [&](int mb, int nb) {                                         \
    __builtin_amdgcn_s_setprio(1);                                            \
    _Pragma("unroll")                                                         \
    for (int dk = 0; dk < 2; ++dk)                                            \
      _Pragma("unroll")                                                       \
      for (int m = 0; m < 4; ++m)                                             \
        _Pragma("unroll")                                                     \
        for (int n = 0; n < 2; ++n)                                           \
          acc[mb + m][nb + n] =                                               \
              mfma16(af[mb + m][dk], bfr[nb + n][dk], acc[mb + m][nb + n]);   \
    __builtin_amdgcn_s_setprio(0);                                            \
  };                                                                          \
  /* prologue: T0 -> buf0, T1 -> buf1 (8 stages, 16 loads) */                 \
  stageA(0, 0, 0); stageA(0, 1, 0); stageB(0, 0, 0); stageB(0, 1, 0);         \
  stageA(1, 0, 1); stageA(1, 1, 1); stageB(1, 0, 1); stageB(1, 1, 1);         \
  VMC(8);                                     /* T0 retired, T1 may fly */    \
  BAR();                                                                      \
  for (int it = 0; it < 8; ++it) {                                            \
    const bool pf = (it < 7);                                                 \
    const int t2 = 2 * it + 2, t3 = 2 * it + 3;                               \
    /* P1: buf0 reads af0-3, bfr0-1; MFMA Q0 */                               \
    readA(0, 0); readB(0, 0);                                                 \
    BAR(); LGKM0();                                                           \
    domfma(0, 0);                                                             \
    BAR();                                                                    \
    /* P2: af4-7; MFMA Q1 (A LDS fully read) */                               \
    readA(0, 4);                                                              \
    BAR(); LGKM0();                                                           \
    domfma(4, 0);                                                             \
    BAR();                                                                    \
    /* P3: bfr2-3; stage A(t2); MFMA Q3 (B LDS fully read) */                 \
    readB(0, 2);                                                              \
    if (pf) { stageA(0, 0, t2); stageA(0, 1, t2); }                           \
    BAR(); LGKM0();                                                           \
    domfma(4, 2);                                                             \
    BAR();                                                                    \
    /* P4: stage B(t2); MFMA Q2; counted wait for buf1 */                     \
    if (pf) { stageB(0, 0, t2); stageB(0, 1, t2); }                           \
    BAR();                                                                    \
    domfma(0, 2);                                                             \
    if (pf) { VMC(8); } else { VMC(0); }                                      \
    BAR();                                                                    \
    /* P5-P8: mirror on buf1 */                                               \
    readA(1, 0); readB(1, 0);                                                 \
    BAR(); LGKM0();                                                           \
    domfma(0, 0);                                                             \
    BAR();                                                                    \
    readA(1, 4);                                                              \
    BAR(); LGKM0();                                                           \
    domfma(4, 0);                                                             \
    BAR();                                                                    \
    readB(1, 2);                                                              \
    if (pf) { stageA(1, 0, t3); stageA(1, 1, t3); }                           \
    BAR(); LGKM0();                                                           \
    domfma(4, 2);                                                             \
    BAR();                                                                    \
    if (pf) { stageB(1, 0, t3); stageB(1, 1, t3); }                           \
    BAR();                                                                    \
    domfma(0, 2);                                                             \
    if (pf) { VMC(8); } else { VMC(0); }                                      \
    BAR();                                                                    \
  }

// ---------------- fused QKV GEMM: 256x256 8-phase, XCD-striped ----------------
__global__ __launch_bounds__(512, 1)
void qkv_gemm(const u16* __restrict__ X, const u16* __restrict__ W,
              u16* __restrict__ Qo, u16* __restrict__ Ko, u16* __restrict__ VTo) {
  __shared__ __align__(16) u16 At[2][2][128 * 64];
  __shared__ __align__(16) u16 Bt[2][2][128 * 64];
  const int tid = threadIdx.x;
  const int w = tid >> 6, lane = tid & 63;
  const int g = lane >> 4, c16 = lane & 15;
  const int wr = w >> 2, wc = w & 3;
  const int lid = blockIdx.x;
  const int xcd = lid & 7, gg = lid >> 3;
  const int M0 = ((xcd << 3) | (gg & 7)) * 256;
  const int N0 = (gg >> 3) * 256;
  const u16* Abase = X + (size_t)M0 * 1024;
  const u16* Bbase = W + (size_t)N0 * 1024;

  f32x4 acc[8][4] = {};
  GEMM8_CORE(Abase, Bbase);

  const int which = N0 >> 10;                  // 0=Q, 1=K, 2=V
  const int colbase = N0 & 1023;
#pragma unroll
  for (int m = 0; m < 8; ++m) {
#pragma unroll
    for (int n = 0; n < 4; ++n) {
#pragma unroll
      for (int r = 0; r < 4; ++r) {
        int gm  = M0 + wr * 128 + m * 16 + 4 * g + r;
        int col = colbase + wc * 64 + n * 16 + c16;
        u16 hv = f2bf(acc[m][n][r]);
        if (which == 0) {
          Qo[(size_t)gm * 1024 + col] = hv;
        } else if (which == 1) {
          Ko[(size_t)gm * 1024 + col] = hv;
        } else {
          int b = gm >> 12, s2 = gm & 4095;
          VTo[((size_t)((b << 10) + col)) * 4096 + s2] = hv;
        }
      }
    }
  }
}

// ---------------- S-GEMM + exp: 256x256 causal tiles, 8-phase, XCD-chunked ----------------
__global__ __launch_bounds__(512, 1)
void sgemm_exp(const u16* __restrict__ Q, const u16* __restrict__ K,
               u16* __restrict__ Spack, float* __restrict__ lpart) {
  __shared__ __align__(16) u16 At[2][2][128 * 64];
  __shared__ __align__(16) u16 Bt[2][2][128 * 64];
  __shared__ float lsum[256][4];
  const int tid = threadIdx.x;
  const int w = tid >> 6, lane = tid & 63;
  const int g = lane >> 4, c16 = lane & 15;
  const int wr = w >> 2, wc = w & 3;
  const int b = blockIdx.y;

  int L = (blockIdx.x & 7) * 17 + (blockIdx.x >> 3);   // bijective XCD chunking
  int qt = 0;
  while ((qt + 1) * (qt + 2) / 2 <= L) ++qt;
  const int kt = L - qt * (qt + 1) / 2;

  const u16* Abase = Q + (size_t)b * 4096 * 1024 + (size_t)qt * 256 * 1024;
  const u16* Bbase = K + (size_t)b * 4096 * 1024 + (size_t)kt * 256 * 1024;

  f32x4 acc[8][4] = {};
  GEMM8_CORE(Abase, Bbase);

  // epilogue: exp + mask, store into 128-tile packed layout, row-sum partials.
  const int qt128 = 2 * qt + wr;
  const int kt128 = 2 * kt + (wc >> 1);
  const bool exists = (kt128 <= qt128);
  u16* Sb = Spack + (((size_t)b * 528 + (size_t)(qt128 * (qt128 + 1)) / 2 + kt128) << 14);
  const int q0 = qt * 256, k0g = kt * 256;
  float psum[8][4];
#pragma unroll
  for (int m = 0; m < 8; ++m)
#pragma unroll
    for (int r = 0; r < 4; ++r) psum[m][r] = 0.f;
#pragma unroll
  for (int m = 0; m < 8; ++m) {
#pragma unroll
    for (int n = 0; n < 4; ++n) {
#pragma unroll
      for (int r = 0; r < 4; ++r) {
        int rl = wr * 128 + m * 16 + 4 * g + r;
        int cl = wc * 64 + n * 16 + c16;
        float s = acc[m][n][r] * 0.03125f;     // 1/sqrt(1024)
        float p = (k0g + cl <= q0 + rl) ? __expf(s) : 0.f;
        u16 pb = f2bf(p);
        if (exists) Sb[(rl & 127) * 128 + (cl & 127)] = pb;
        psum[m][r] += bf2f(pb);
      }
    }
  }
#pragma unroll
  for (int m = 0; m < 8; ++m)
#pragma unroll
    for (int r = 0; r < 4; ++r) {
      float v = psum[m][r];
      v += __shfl_xor(v, 1, 64);
      v += __shfl_xor(v, 2, 64);
      v += __shfl_xor(v, 4, 64);
      v += __shfl_xor(v, 8, 64);
      psum[m][r] = v;
    }
  if (c16 == 0) {
#pragma unroll
    for (int m = 0; m < 8; ++m)
#pragma unroll
      for (int r = 0; r < 4; ++r)
        lsum[wr * 128 + m * 16 + 4 * g + r][wc] = psum[m][r];
  }
  __syncthreads();
  if (tid < 256) {
    float v = lsum[tid][0] + lsum[tid][1] + lsum[tid][2] + lsum[tid][3];
    lpart[((size_t)b * 4096 + q0 + tid) * 16 + kt] = v;
  }
}

// ---------------- PV GEMM: 256x128 paired q-tiles, fused l-reduce (R9 proven) ----------------
__global__ __launch_bounds__(512)
void pv_gemm(const u16* __restrict__ Spack, const u16* __restrict__ VT,
             const u16* __restrict__ ztile, const float* __restrict__ lpart,
             float* __restrict__ Out) {
  __shared__ __align__(16) u16 At[2][256 * 64];
  __shared__ __align__(16) u16 Bt[2][128 * 64];
  __shared__ float linv_lds[512];
  const int tid = threadIdx.x;
  const int w = tid >> 6, lane = tid & 63;
  const int g = lane >> 4, c16 = lane & 15;
  const int wm = w >> 1, wn = w & 1;
  const int pp = blockIdx.x;
  const int d0 = blockIdx.y;
  const int b  = blockIdx.z;

  const u16* Sp_b = Spack + (size_t)b * 528 * 16384;
  const u16* VTb  = VT + (size_t)b * 1024 * 4096;
  float* Ob = Out + (size_t)b * 4096 * 1024;

  {
    const int QTr = (tid < 256) ? pp : (15 - pp);
    const int row = QTr * 256 + (tid & 255);
    const int nt  = QTr + 1;
    const float* p = lpart + ((size_t)b * 4096 + row) * 16;
    float s = 0.f;
    for (int i = 0; i < nt; ++i) s += p[i];
    linv_lds[tid] = 1.f / s;
  }

  for (int pass = 0; pass < 2; ++pass) {
    const int QT = pass == 0 ? pp : 15 - pp;
    const int M0 = QT * 256;
    const int nsteps = (QT + 1) * 4;
    const int tLo = 2 * QT;
    const size_t triLo = (size_t)(tLo * (tLo + 1)) / 2;
    const size_t triHi = (size_t)((tLo + 1) * (tLo + 2)) / 2;

    f32x4 acc[4][4] = {};

    auto stage = [&](int s, int tt) {
      const int kv0 = tt * 64;
      const int kt128 = tt >> 1;
      const int koff = (tt & 1) * 64;
      const u16* baseLo = (kt128 <= tLo) ? Sp_b + ((triLo + kt128) << 14) : ztile;
      const u16* baseHi = Sp_b + ((triHi + kt128) << 14);
#pragma unroll
      for (int i = 0; i < 4; ++i) {
        int ci = i * 512 + tid;
        int r = ci >> 3;
        int c = (ci & 7) ^ (r & 7);
        const u16* base = (i < 2) ? baseLo : baseHi;
        gld_lds16(base + (size_t)(r & 127) * 128 + koff + c * 8, &At[s][ci * 8]);
      }
#pragma unroll
      for (int i = 0; i < 2; ++i) {
        int ci = i * 512 + tid;
        int r = ci >> 3;
        int c = (ci & 7) ^ (r & 7);
        gld_lds16(VTb + (size_t)(d0 * 128 + r) * 4096 + kv0 + c * 8, &Bt[s][ci * 8]);
      }
    };
    auto compute = [&](int s) {
#pragma unroll
      for (int dk = 0; dk < 2; ++dk) {
        bf16x8 af2[4], bf2[4];
#pragma unroll
        for (int m = 0; m < 4; ++m) {
          int row = wm * 64 + m * 16 + c16;
          int ch = dk * 4 + g;
          af2[m] = *(const bf16x8*)&At[s][row * 64 + ((ch ^ (row & 7)) * 8)];
        }
#pragma unroll
        for (int n = 0; n < 4; ++n) {
          int row = wn * 64 + n * 16 + c16;
          int ch = dk * 4 + g;
          bf2[n] = *(const bf16x8*)&Bt[s][row * 64 + ((ch ^ (row & 7)) * 8)];
        }
#pragma unroll
        for (int m = 0; m < 4; ++m)
#pragma unroll
          for (int n = 0; n < 4; ++n)
            acc[m][n] = mfma16(af2[m], bf2[n], acc[m][n]);
      }
    };

    stage(0, 0);
    __syncthreads();
    int cur = 0;
    for (int t = 0; t < nsteps; ++t) {
      if (t + 1 < nsteps) stage(cur ^ 1, t + 1);
      compute(cur);
      __syncthreads();
      cur ^= 1;
    }

    const float* lb = linv_lds + pass * 256;
#pragma unroll
    for (int m = 0; m < 4; ++m) {
#pragma unroll
      for (int r = 0; r < 4; ++r) {
        int rl = wm * 64 + m * 16 + 4 * g + r;
        float li = lb[rl];
#pragma unroll
        for (int n = 0; n < 4; ++n) {
          int dcol = d0 * 128 + wn * 64 + n * 16 + c16;
          Ob[(size_t)(M0 + rl) * 1024 + dcol] = acc[m][n][r] * li;
        }
      }
    }
  }
}

// ---------------- fallback attn (R1, proven 558us) ----------------
__global__ __launch_bounds__(512, 2)
void attn_kernel(const u16* __restrict__ Q, const u16* __restrict__ K,
                 const u16* __restrict__ VT, float* __restrict__ Out) {
  __shared__ u16 kv_lds[32 * 1024];
  __shared__ float s_part[4][32][33];
  __shared__ u16 p_lds[32 * 40];
  __shared__ float l_lds[32];

  const int tid = threadIdx.x;
  const int w = tid >> 6, lane = tid & 63;
  const int g = lane >> 4, c16 = lane & 15;
  const int b  = blockIdx.x & 3;
  const int qb = 127 - (blockIdx.x >> 2);
  const int qs = qb * 32;
  const int kh = w & 1, dq = w >> 1;

  const u16* Qb  = Q  + (size_t)b * 4096 * 1024;
  const u16* Kb  = K  + (size_t)b * 4096 * 1024;
  const u16* VTb = VT + (size_t)b * 1024 * 4096;

  bf16x8 qfrag[2][8];
#pragma unroll
  for (int qh = 0; qh < 2; ++qh)
#pragma unroll
    for (int dk = 0; dk < 8; ++dk)
      qfrag[qh][dk] = *(const bf16x8*)(Qb + (size_t)(qs + qh * 16 + c16) * 1024
                                       + dq * 256 + dk * 32 + g * 8);

  f32x4 oacc[2][8] = {};
  if (tid < 32) l_lds[tid] = 0.f;

  const int qrow_p = tid >> 4;
  const int kk     = tid & 15;
  const int gq     = qs + qrow_p;

  for (int j = 0; j <= qb; ++j) {
    const int kv0 = j * 32;
    __syncthreads();
    uint4 rk[8];
#pragma unroll
    for (int i = 0; i < 8; ++i) {
      int ci = i * 512 + tid;
      int r  = ci >> 7;
      int c  = (ci & 127) ^ (r & 7);
      rk[i] = *(const uint4*)(Kb + (size_t)(kv0 + r) * 1024 + c * 8);
    }
#pragma unroll
    for (int i = 0; i < 8; ++i)
      *(uint4*)&kv_lds[(size_t)(i * 512 + tid) * 8] = rk[i];
    __syncthreads();
    f32x4 sacc[2] = {};
#pragma unroll
    for (int dk = 0; dk < 8; ++dk) {
      int kvrow = kh * 16 + c16;
      int ch    = dq * 32 + dk * 4 + g;
      bf16x8 kf = *(const bf16x8*)&kv_lds[kvrow * 1024 + ((ch ^ (kvrow & 7)) * 8)];
      sacc[0] = mfma16(qfrag[0][dk], kf, sacc[0]);
      sacc[1] = mfma16(qfrag[1][dk], kf, sacc[1]);
    }
#pragma unroll
    for (int qh = 0; qh < 2; ++qh)
#pragma unroll
      for (int r = 0; r < 4; ++r)
        s_part[dq][qh * 16 + 4 * g + r][kh * 16 + c16] = sacc[qh][r];
    __syncthreads();
    uint4 rv[8];
#pragma unroll
    for (int i = 0; i < 8; ++i) {
      int ci = i * 512 + tid;
      int d  = ((ci >> 6) << 4) + (ci & 15);
      int c  = (ci >> 4) & 3;
      rv[i] = *(const uint4*)(VTb + (size_t)d * 4096 + kv0 + c * 8);
    }
    {
      float psum = 0.f;
#pragma unroll
      for (int h = 0; h < 2; ++h) {
        int kcol = kk + h * 16;
        float s = s_part[0][qrow_p][kcol] + s_part[1][qrow_p][kcol]
                + s_part[2][qrow_p][kcol] + s_part[3][qrow_p][kcol];
        s *= 0.03125f;
        float p = (kv0 + kcol <= gq) ? __expf(s) : 0.f;
        u16 pb = f2bf(p);
        p_lds[qrow_p * 40 + kcol] = pb;
        psum += bf2f(pb);
      }
#pragma unroll
      for (int off = 1; off < 16; off <<= 1)
        psum += __shfl_xor(psum, off, 64);
      if (kk == 0) l_lds[qrow_p] += psum;
    }
#pragma unroll
    for (int i = 0; i < 8; ++i)
      *(uint4*)&kv_lds[(size_t)(i * 512 + tid) * 8] = rv[i];
    __syncthreads();
    bf16x8 pa0 = *(const bf16x8*)&p_lds[(0  + c16) * 40 + g * 8];
    bf16x8 pa1 = *(const bf16x8*)&p_lds[(16 + c16) * 40 + g * 8];
#pragma unroll
    for (int f = 0; f < 8; ++f) {
      int dcol = w * 128 + f * 16 + c16;
      int pos  = (dcol >> 4) * 64 + g * 16 + (dcol & 15);
      bf16x8 vf = *(const bf16x8*)&kv_lds[(size_t)pos * 8];
      oacc[0][f] = mfma16(pa0, vf, oacc[0][f]);
      oacc[1][f] = mfma16(pa1, vf, oacc[1][f]);
    }
  }

  float* Ob = Out + (size_t)b * 4096 * 1024;
#pragma unroll
  for (int qh = 0; qh < 2; ++qh) {
#pragma unroll
    for (int r = 0; r < 4; ++r) {
      int ql = qh * 16 + 4 * g + r;
      float linvv = 1.f / l_lds[ql];
#pragma unroll
      for (int f = 0; f < 8; ++f)
        Ob[(size_t)(qs + ql) * 1024 + w * 128 + f * 16 + c16] = oacc[qh][f][r] * linvv;
    }
  }
}

extern "C" void kernel_launch(void* const* d_in, const int* in_sizes, int n_in,
                              void* d_out, int out_size, void* d_ws, size_t ws_size,
                              hipStream_t stream) {
  const float* x  = (const float*)d_in[0];
  const float* Wq = (const float*)d_in[1];
  const float* Wk = (const float*)d_in[2];
  const float* Wv = (const float*)d_in[3];
  float* out = (float*)d_out;

  u16* ws    = (u16*)d_ws;
  u16* wWqkv = ws;                                   // 3M elems
  u16* wX    = wWqkv + (size_t)3 * 1024 * 1024;      // dead after qkv -> zero tile
  u16* wQ    = wX + (size_t)16384 * 1024;
  u16* wK    = wQ + (size_t)16384 * 1024;
  u16* wVT   = wK + (size_t)16384 * 1024;            // [4][1024][4096]
  u16* wSp   = wVT + (size_t)16384 * 1024;           // packed 128-tile triangle
  float* lpart = (float*)(ws + (size_t)104857600);   // 16384*16 f32 (1MB)

  cast_all<<<dim3(9728), 256, 0, stream>>>(x, Wq, Wk, Wv, wX, wWqkv);

  qkv_gemm<<<dim3(768), 512, 0, stream>>>(wX, wWqkv, wQ, wK, wVT);

  if (ws_size >= (size_t)211877888) {
    hipMemsetAsync(wX, 0, 32768, stream);            // zero tile for absent causal tiles
    sgemm_exp<<<dim3(136, 4), 512, 0, stream>>>(wQ, wK, wSp, lpart);
    pv_gemm<<<dim3(8, 8, 4), 512, 0, stream>>>(wSp, wVT, wX, lpart, out);
  } else {
    attn_kernel<<<dim3(512), 512, 0, stream>>>(wQ, wK, wVT, out);
  }
}

// Round 11
// 356.104 us; speedup vs baseline: 1.2982x; 1.0334x over previous
//
#include <hip/hip_runtime.h>

// CausalAttention: B=4, S=4096, D=1024 (single head, head_dim=1024)
// v11: fused-cast -> QKV GEMM (VT, XCD-striped, 8-phase) -> S-GEMM+exp
//     (causal triangle, XCD-chunked, 8-phase) -> PV GEMM (fused l-reduce,
//     8-phase). No-max softmax (validated R1).
// R11: pv_gemm ported to the R10-validated 8-phase counted-vmcnt schedule
// (stage-to-use distance 4-5 phases; vmcnt(6) at P4/P8 = exactly one 6-load
// stage-set in flight; loads never drained mid-loop). qkv/sgemm = R10.
// ws (u16 elems): Wqkv[3M] | X[16M, zero-tile after qkv] | Q[16M] | K[16M] |
//   VT[16M] | Spack[34.6M packed 128-tiles] | lpart[16384*16 f32]

typedef unsigned short u16;
typedef unsigned int u32;
typedef __attribute__((ext_vector_type(8))) short bf16x8;
typedef __attribute__((ext_vector_type(4))) float f32x4;
typedef __attribute__((ext_vector_type(8))) unsigned short u16x8;

__device__ __forceinline__ u16 f2bf(float f) {
  union { float f; unsigned u; } v; v.f = f;
  unsigned r = v.u + 0x7FFFu + ((v.u >> 16) & 1u);  // RNE
  return (u16)(r >> 16);
}
__device__ __forceinline__ float bf2f(u16 h) {
  union { unsigned u; float f; } v; v.u = ((unsigned)h) << 16;
  return v.f;
}
__device__ __forceinline__ f32x4 mfma16(bf16x8 a, bf16x8 b, f32x4 c) {
  return __builtin_amdgcn_mfma_f32_16x16x32_bf16(a, b, c, 0, 0, 0);
}
__device__ __forceinline__ void gld_lds16(const u16* g, u16* l) {
  __builtin_amdgcn_global_load_lds(
      (const __attribute__((address_space(1))) u32*)g,
      (__attribute__((address_space(3))) u32*)l, 16, 0, 0);
}
#define BAR() do { __builtin_amdgcn_s_barrier(); \
                   __builtin_amdgcn_sched_barrier(0); } while (0)
#define LGKM0() do { asm volatile("s_waitcnt lgkmcnt(0)" ::: "memory"); \
                     __builtin_amdgcn_sched_barrier(0); } while (0)
#define VMC(n) asm volatile("s_waitcnt vmcnt(" #n ")" ::: "memory")

// ---------------- fused cast f32 -> bf16 (x, Wq, Wk, Wv in one launch) ----------------
__global__ __launch_bounds__(256)
void cast_all(const float* __restrict__ x, const float* __restrict__ Wq,
              const float* __restrict__ Wk, const float* __restrict__ Wv,
              u16* __restrict__ wX, u16* __restrict__ wWqkv) {
  int i = blockIdx.x * 256 + threadIdx.x;
  const float* src; u16* dst; int j;
  if (i < 2097152)        { src = x;  dst = wX;                j = i; }
  else if (i < 2228224)   { src = Wq; dst = wWqkv;             j = i - 2097152; }
  else if (i < 2359296)   { src = Wk; dst = wWqkv + 1048576;   j = i - 2228224; }
  else if (i < 2490368)   { src = Wv; dst = wWqkv + 2097152;   j = i - 2359296; }
  else return;
  const float4* s4 = (const float4*)src;
  float4 a = s4[2*j], b = s4[2*j+1];
  u16x8 o;
  o[0]=f2bf(a.x); o[1]=f2bf(a.y); o[2]=f2bf(a.z); o[3]=f2bf(a.w);
  o[4]=f2bf(b.x); o[5]=f2bf(b.y); o[6]=f2bf(b.z); o[7]=f2bf(b.w);
  ((u16x8*)dst)[j] = o;
}

// 8-phase GEMM core (qkv / sgemm shared). 256x256 tile, 8 waves (wr 2M x wc 4N),
// BK=64, 2 K-tiles per iteration. Reads: P1 af[0-3]+bfr[0-1], P2 af[4-7],
// P3 bfr[2-3]. Stages: P3 A(t+2), P4 B(t+2), P7 A(t+3), P8 B(t+3).
// vmcnt(8) at P4/P8 (R10-validated).
#define GEMM8_CORE(Abase, Bbase)                                              \
  auto stageA = [&](int bufi, int h, int t) {                                 \
    _Pragma("unroll")                                                         \
    for (int i = 0; i < 2; ++i) {                                             \
      int ci = i * 512 + tid;                                                 \
      int r  = ci >> 3;                                                       \
      int c  = (ci & 7) ^ (r & 7);                                            \
      gld_lds16(Abase + (size_t)(h * 128 + r) * 1024 + t * 64 + c * 8,        \
                &At[bufi][h][ci * 8]);                                        \
    }                                                                         \
  };                                                                          \
  auto stageB = [&](int bufi, int h, int t) {                                 \
    _Pragma("unroll")                                                         \
    for (int i = 0; i < 2; ++i) {                                             \
      int ci = i * 512 + tid;                                                 \
      int r  = ci >> 3;                                                       \
      int c  = (ci & 7) ^ (r & 7);                                            \
      gld_lds16(Bbase + (size_t)(h * 128 + r) * 1024 + t * 64 + c * 8,        \
                &Bt[bufi][h][ci * 8]);                                        \
    }                                                                         \
  };                                                                          \
  bf16x8 af[8][2], bfr[4][2];                                                 \
  auto readA = [&](int bufi, int mb) {                                        \
    _Pragma("unroll")                                                         \
    for (int m = 0; m < 4; ++m)                                               \
      _Pragma("unroll")                                                       \
      for (int dk = 0; dk < 2; ++dk) {                                        \
        int r  = (mb + m) * 16 + c16;                                         \
        int ch = dk * 4 + g;                                                  \
        af[mb + m][dk] =                                                      \
            *(const bf16x8*)&At[bufi][wr][r * 64 + ((ch ^ (r & 7)) * 8)];     \
      }                                                                       \
  };                                                                          \
  auto readB = [&](int bufi, int nb) {                                        \
    _Pragma("unroll")                                                         \
    for (int n = 0; n < 2; ++n)                                               \
      _Pragma("unroll")                                                       \
      for (int dk = 0; dk < 2; ++dk) {                                        \
        int r  = (wc & 1) * 64 + (nb + n) * 16 + c16;                         \
        int ch = dk * 4 + g;                                                  \
        bfr[nb + n][dk] =                                                     \
            *(const bf16x8*)&Bt[bufi][wc >> 1][r * 64 + ((ch ^ (r & 7)) * 8)];\
      }                                                                       \
  };                                                                          \
  auto domfma = [&](int mb, int nb) {                                         \
    __builtin_amdgcn_s_setprio(1);                                            \
    _Pragma("unroll")                                                         \
    for (int dk = 0; dk < 2; ++dk)                                            \
      _Pragma("unroll")                                                       \
      for (int m = 0; m < 4; ++m)                                             \
        _Pragma("unroll")                                                     \
        for (int n = 0; n < 2; ++n)                                           \
          acc[mb + m][nb + n] =                                               \
              mfma16(af[mb + m][dk], bfr[nb + n][dk], acc[mb + m][nb + n]);   \
    __builtin_amdgcn_s_setprio(0);                                            \
  };                                                                          \
  stageA(0, 0, 0); stageA(0, 1, 0); stageB(0, 0, 0); stageB(0, 1, 0);         \
  stageA(1, 0, 1); stageA(1, 1, 1); stageB(1, 0, 1); stageB(1, 1, 1);         \
  VMC(8);                                                                     \
  BAR();                                                                      \
  for (int it = 0; it < 8; ++it) {                                            \
    const bool pf = (it < 7);                                                 \
    const int t2 = 2 * it + 2, t3 = 2 * it + 3;                               \
    readA(0, 0); readB(0, 0);                                                 \
    BAR(); LGKM0();                                                           \
    domfma(0, 0);                                                             \
    BAR();                                                                    \
    readA(0, 4);                                                              \
    BAR(); LGKM0();                                                           \
    domfma(4, 0);                                                             \
    BAR();                                                                    \
    readB(0, 2);                                                              \
    if (pf) { stageA(0, 0, t2); stageA(0, 1, t2); }                           \
    BAR(); LGKM0();                                                           \
    domfma(4, 2);                                                             \
    BAR();                                                                    \
    if (pf) { stageB(0, 0, t2); stageB(0, 1, t2); }                           \
    BAR();                                                                    \
    domfma(0, 2);                                                             \
    if (pf) { VMC(8); } else { VMC(0); }                                      \
    BAR();                                                                    \
    readA(1, 0); readB(1, 0);                                                 \
    BAR(); LGKM0();                                                           \
    domfma(0, 0);                                                             \
    BAR();                                                                    \
    readA(1, 4);                                                              \
    BAR(); LGKM0();                                                           \
    domfma(4, 0);                                                             \
    BAR();                                                                    \
    readB(1, 2);                                                              \
    if (pf) { stageA(1, 0, t3); stageA(1, 1, t3); }                           \
    BAR(); LGKM0();                                                           \
    domfma(4, 2);                                                             \
    BAR();                                                                    \
    if (pf) { stageB(1, 0, t3); stageB(1, 1, t3); }                           \
    BAR();                                                                    \
    domfma(0, 2);                                                             \
    if (pf) { VMC(8); } else { VMC(0); }                                      \
    BAR();                                                                    \
  }

// ---------------- fused QKV GEMM: 256x256 8-phase, XCD-striped ----------------
__global__ __launch_bounds__(512, 1)
void qkv_gemm(const u16* __restrict__ X, const u16* __restrict__ W,
              u16* __restrict__ Qo, u16* __restrict__ Ko, u16* __restrict__ VTo) {
  __shared__ __align__(16) u16 At[2][2][128 * 64];
  __shared__ __align__(16) u16 Bt[2][2][128 * 64];
  const int tid = threadIdx.x;
  const int w = tid >> 6, lane = tid & 63;
  const int g = lane >> 4, c16 = lane & 15;
  const int wr = w >> 2, wc = w & 3;
  const int lid = blockIdx.x;
  const int xcd = lid & 7, gg = lid >> 3;
  const int M0 = ((xcd << 3) | (gg & 7)) * 256;
  const int N0 = (gg >> 3) * 256;
  const u16* Abase = X + (size_t)M0 * 1024;
  const u16* Bbase = W + (size_t)N0 * 1024;

  f32x4 acc[8][4] = {};
  GEMM8_CORE(Abase, Bbase);

  const int which = N0 >> 10;                  // 0=Q, 1=K, 2=V
  const int colbase = N0 & 1023;
#pragma unroll
  for (int m = 0; m < 8; ++m) {
#pragma unroll
    for (int n = 0; n < 4; ++n) {
#pragma unroll
      for (int r = 0; r < 4; ++r) {
        int gm  = M0 + wr * 128 + m * 16 + 4 * g + r;
        int col = colbase + wc * 64 + n * 16 + c16;
        u16 hv = f2bf(acc[m][n][r]);
        if (which == 0) {
          Qo[(size_t)gm * 1024 + col] = hv;
        } else if (which == 1) {
          Ko[(size_t)gm * 1024 + col] = hv;
        } else {
          int b = gm >> 12, s2 = gm & 4095;
          VTo[((size_t)((b << 10) + col)) * 4096 + s2] = hv;
        }
      }
    }
  }
}

// ---------------- S-GEMM + exp: 256x256 causal tiles, 8-phase, XCD-chunked ----------------
__global__ __launch_bounds__(512, 1)
void sgemm_exp(const u16* __restrict__ Q, const u16* __restrict__ K,
               u16* __restrict__ Spack, float* __restrict__ lpart) {
  __shared__ __align__(16) u16 At[2][2][128 * 64];
  __shared__ __align__(16) u16 Bt[2][2][128 * 64];
  __shared__ float lsum[256][4];
  const int tid = threadIdx.x;
  const int w = tid >> 6, lane = tid & 63;
  const int g = lane >> 4, c16 = lane & 15;
  const int wr = w >> 2, wc = w & 3;
  const int b = blockIdx.y;

  int L = (blockIdx.x & 7) * 17 + (blockIdx.x >> 3);   // bijective XCD chunking
  int qt = 0;
  while ((qt + 1) * (qt + 2) / 2 <= L) ++qt;
  const int kt = L - qt * (qt + 1) / 2;

  const u16* Abase = Q + (size_t)b * 4096 * 1024 + (size_t)qt * 256 * 1024;
  const u16* Bbase = K + (size_t)b * 4096 * 1024 + (size_t)kt * 256 * 1024;

  f32x4 acc[8][4] = {};
  GEMM8_CORE(Abase, Bbase);

  // epilogue: exp + mask, store into 128-tile packed layout, row-sum partials.
  const int qt128 = 2 * qt + wr;
  const int kt128 = 2 * kt + (wc >> 1);
  const bool exists = (kt128 <= qt128);
  u16* Sb = Spack + (((size_t)b * 528 + (size_t)(qt128 * (qt128 + 1)) / 2 + kt128) << 14);
  const int q0 = qt * 256, k0g = kt * 256;
  float psum[8][4];
#pragma unroll
  for (int m = 0; m < 8; ++m)
#pragma unroll
    for (int r = 0; r < 4; ++r) psum[m][r] = 0.f;
#pragma unroll
  for (int m = 0; m < 8; ++m) {
#pragma unroll
    for (int n = 0; n < 4; ++n) {
#pragma unroll
      for (int r = 0; r < 4; ++r) {
        int rl = wr * 128 + m * 16 + 4 * g + r;
        int cl = wc * 64 + n * 16 + c16;
        float s = acc[m][n][r] * 0.03125f;     // 1/sqrt(1024)
        float p = (k0g + cl <= q0 + rl) ? __expf(s) : 0.f;
        u16 pb = f2bf(p);
        if (exists) Sb[(rl & 127) * 128 + (cl & 127)] = pb;
        psum[m][r] += bf2f(pb);
      }
    }
  }
#pragma unroll
  for (int m = 0; m < 8; ++m)
#pragma unroll
    for (int r = 0; r < 4; ++r) {
      float v = psum[m][r];
      v += __shfl_xor(v, 1, 64);
      v += __shfl_xor(v, 2, 64);
      v += __shfl_xor(v, 4, 64);
      v += __shfl_xor(v, 8, 64);
      psum[m][r] = v;
    }
  if (c16 == 0) {
#pragma unroll
    for (int m = 0; m < 8; ++m)
#pragma unroll
      for (int r = 0; r < 4; ++r)
        lsum[wr * 128 + m * 16 + 4 * g + r][wc] = psum[m][r];
  }
  __syncthreads();
  if (tid < 256) {
    float v = lsum[tid][0] + lsum[tid][1] + lsum[tid][2] + lsum[tid][3];
    lpart[((size_t)b * 4096 + q0 + tid) * 16 + kt] = v;
  }
}

// ---------------- PV GEMM: 256x128 paired q-tiles, 8-phase, fused l-reduce ----------------
// 8 waves as 4M x 2N (wave tile 64x64). Stage-set per K-step = A-lo/A-hi/B
// (6 loads). Stages at P3 (A) / P4 (B); vmcnt(6) at P4/P8.
__global__ __launch_bounds__(512, 1)
void pv_gemm(const u16* __restrict__ Spack, const u16* __restrict__ VT,
             const u16* __restrict__ ztile, const float* __restrict__ lpart,
             float* __restrict__ Out) {
  __shared__ __align__(16) u16 At[2][256 * 64];
  __shared__ __align__(16) u16 Bt[2][128 * 64];
  __shared__ float linv_lds[512];
  const int tid = threadIdx.x;
  const int w = tid >> 6, lane = tid & 63;
  const int g = lane >> 4, c16 = lane & 15;
  const int wm = w >> 1, wn = w & 1;           // wave tile: rows wm*64, cols wn*64
  const int pp = blockIdx.x;
  const int d0 = blockIdx.y;
  const int b  = blockIdx.z;

  const u16* Sp_b = Spack + (size_t)b * 528 * 16384;
  const u16* VTb  = VT + (size_t)b * 1024 * 4096;
  float* Ob = Out + (size_t)b * 4096 * 1024;

  // fused l-reduce
  {
    const int QTr = (tid < 256) ? pp : (15 - pp);
    const int row = QTr * 256 + (tid & 255);
    const int nt  = QTr + 1;
    const float* p = lpart + ((size_t)b * 4096 + row) * 16;
    float s = 0.f;
    for (int i = 0; i < nt; ++i) s += p[i];
    linv_lds[tid] = 1.f / s;
  }

  for (int pass = 0; pass < 2; ++pass) {
    const int QT = pass == 0 ? pp : 15 - pp;
    const int M0 = QT * 256;
    const int nsteps = (QT + 1) * 4;           // K-steps of 64 (even)
    const int niter  = nsteps >> 1;
    const int tLo = 2 * QT;
    const size_t triLo = (size_t)(tLo * (tLo + 1)) / 2;
    const size_t triHi = (size_t)((tLo + 1) * (tLo + 2)) / 2;

    f32x4 acc[4][4] = {};

    // stage granules for K-step tt into buffer bufi
    auto stA = [&](int bufi, int half, int tt) {   // half 0: rows 0-127, 1: 128-255
      const int kt128 = tt >> 1;
      const int koff = (tt & 1) * 64;
      const u16* base;
      if (half == 0) base = (kt128 <= tLo) ? Sp_b + ((triLo + kt128) << 14) : ztile;
      else           base = Sp_b + ((triHi + kt128) << 14);
#pragma unroll
      for (int i = 0; i < 2; ++i) {
        int ci = (half * 2 + i) * 512 + tid;
        int r = ci >> 3;
        int c = (ci & 7) ^ (r & 7);
        gld_lds16(base + (size_t)(r & 127) * 128 + koff + c * 8, &At[bufi][ci * 8]);
      }
    };
    auto stB = [&](int bufi, int tt) {
      const int kv0 = tt * 64;
#pragma unroll
      for (int i = 0; i < 2; ++i) {
        int ci = i * 512 + tid;
        int r = ci >> 3;
        int c = (ci & 7) ^ (r & 7);
        gld_lds16(VTb + (size_t)(d0 * 128 + r) * 4096 + kv0 + c * 8, &Bt[bufi][ci * 8]);
      }
    };

    bf16x8 af[4][2], bfr[4][2];
    auto readA = [&](int bufi, int mb) {
#pragma unroll
      for (int m = 0; m < 2; ++m)
#pragma unroll
        for (int dk = 0; dk < 2; ++dk) {
          int row = wm * 64 + (mb + m) * 16 + c16;
          int ch = dk * 4 + g;
          af[mb + m][dk] = *(const bf16x8*)&At[bufi][row * 64 + ((ch ^ (row & 7)) * 8)];
        }
    };
    auto readB = [&](int bufi, int nb) {
#pragma unroll
      for (int n = 0; n < 2; ++n)
#pragma unroll
        for (int dk = 0; dk < 2; ++dk) {
          int row = wn * 64 + (nb + n) * 16 + c16;
          int ch = dk * 4 + g;
          bfr[nb + n][dk] = *(const bf16x8*)&Bt[bufi][row * 64 + ((ch ^ (row & 7)) * 8)];
        }
    };
    auto domfma = [&](int mb, int nb) {
      __builtin_amdgcn_s_setprio(1);
#pragma unroll
      for (int dk = 0; dk < 2; ++dk)
#pragma unroll
        for (int m = 0; m < 2; ++m)
#pragma unroll
          for (int n = 0; n < 2; ++n)
            acc[mb + m][nb + n] = mfma16(af[mb + m][dk], bfr[nb + n][dk], acc[mb + m][nb + n]);
      __builtin_amdgcn_s_setprio(0);
    };

    // prologue: K-step 0 -> buf0, 1 -> buf1 (6 loads each)
    stA(0, 0, 0); stA(0, 1, 0); stB(0, 0);
    stA(1, 0, 1); stA(1, 1, 1); stB(1, 1);
    VMC(6);
    BAR();
    for (int it = 0; it < niter; ++it) {
      const bool pf = (it + 1 < niter);
      const int t2 = 2 * it + 2, t3 = 2 * it + 3;
      // P1
      readA(0, 0); readB(0, 0);
      BAR(); LGKM0();
      domfma(0, 0);
      BAR();
      // P2
      readA(0, 2);
      BAR(); LGKM0();
      domfma(2, 0);
      BAR();
      // P3 (+ stage A(t2))
      readB(0, 2);
      if (pf) { stA(0, 0, t2); stA(0, 1, t2); }
      BAR(); LGKM0();
      domfma(2, 2);
      BAR();
      // P4 (+ stage B(t2), counted wait)
      if (pf) stB(0, t2);
      BAR();
      domfma(0, 2);
      if (pf) { VMC(6); } else { VMC(0); }
      BAR();
      // P5-P8 mirror on buf1
      readA(1, 0); readB(1, 0);
      BAR(); LGKM0();
      domfma(0, 0);
      BAR();
      readA(1, 2);
      BAR(); LGKM0();
      domfma(2, 0);
      BAR();
      readB(1, 2);
      if (pf) { stA(1, 0, t3); stA(1, 1, t3); }
      BAR(); LGKM0();
      domfma(2, 2);
      BAR();
      if (pf) stB(1, t3);
      BAR();
      domfma(0, 2);
      if (pf) { VMC(6); } else { VMC(0); }
      BAR();
    }

    const float* lb = linv_lds + pass * 256;
#pragma unroll
    for (int m = 0; m < 4; ++m) {
#pragma unroll
      for (int r = 0; r < 4; ++r) {
        int rl = wm * 64 + m * 16 + 4 * g + r;
        float li = lb[rl];
#pragma unroll
        for (int n = 0; n < 4; ++n) {
          int dcol = d0 * 128 + wn * 64 + n * 16 + c16;
          Ob[(size_t)(M0 + rl) * 1024 + dcol] = acc[m][n][r] * li;
        }
      }
    }
  }
}

// ---------------- fallback attn (R1, proven 558us) ----------------
__global__ __launch_bounds__(512, 2)
void attn_kernel(const u16* __restrict__ Q, const u16* __restrict__ K,
                 const u16* __restrict__ VT, float* __restrict__ Out) {
  __shared__ u16 kv_lds[32 * 1024];
  __shared__ float s_part[4][32][33];
  __shared__ u16 p_lds[32 * 40];
  __shared__ float l_lds[32];

  const int tid = threadIdx.x;
  const int w = tid >> 6, lane = tid & 63;
  const int g = lane >> 4, c16 = lane & 15;
  const int b  = blockIdx.x & 3;
  const int qb = 127 - (blockIdx.x >> 2);
  const int qs = qb * 32;
  const int kh = w & 1, dq = w >> 1;

  const u16* Qb  = Q  + (size_t)b * 4096 * 1024;
  const u16* Kb  = K  + (size_t)b * 4096 * 1024;
  const u16* VTb = VT + (size_t)b * 1024 * 4096;

  bf16x8 qfrag[2][8];
#pragma unroll
  for (int qh = 0; qh < 2; ++qh)
#pragma unroll
    for (int dk = 0; dk < 8; ++dk)
      qfrag[qh][dk] = *(const bf16x8*)(Qb + (size_t)(qs + qh * 16 + c16) * 1024
                                       + dq * 256 + dk * 32 + g * 8);

  f32x4 oacc[2][8] = {};
  if (tid < 32) l_lds[tid] = 0.f;

  const int qrow_p = tid >> 4;
  const int kk     = tid & 15;
  const int gq     = qs + qrow_p;

  for (int j = 0; j <= qb; ++j) {
    const int kv0 = j * 32;
    __syncthreads();
    uint4 rk[8];
#pragma unroll
    for (int i = 0; i < 8; ++i) {
      int ci = i * 512 + tid;
      int r  = ci >> 7;
      int c  = (ci & 127) ^ (r & 7);
      rk[i] = *(const uint4*)(Kb + (size_t)(kv0 + r) * 1024 + c * 8);
    }
#pragma unroll
    for (int i = 0; i < 8; ++i)
      *(uint4*)&kv_lds[(size_t)(i * 512 + tid) * 8] = rk[i];
    __syncthreads();
    f32x4 sacc[2] = {};
#pragma unroll
    for (int dk = 0; dk < 8; ++dk) {
      int kvrow = kh * 16 + c16;
      int ch    = dq * 32 + dk * 4 + g;
      bf16x8 kf = *(const bf16x8*)&kv_lds[kvrow * 1024 + ((ch ^ (kvrow & 7)) * 8)];
      sacc[0] = mfma16(qfrag[0][dk], kf, sacc[0]);
      sacc[1] = mfma16(qfrag[1][dk], kf, sacc[1]);
    }
#pragma unroll
    for (int qh = 0; qh < 2; ++qh)
#pragma unroll
      for (int r = 0; r < 4; ++r)
        s_part[dq][qh * 16 + 4 * g + r][kh * 16 + c16] = sacc[qh][r];
    __syncthreads();
    uint4 rv[8];
#pragma unroll
    for (int i = 0; i < 8; ++i) {
      int ci = i * 512 + tid;
      int d  = ((ci >> 6) << 4) + (ci & 15);
      int c  = (ci >> 4) & 3;
      rv[i] = *(const uint4*)(VTb + (size_t)d * 4096 + kv0 + c * 8);
    }
    {
      float psum = 0.f;
#pragma unroll
      for (int h = 0; h < 2; ++h) {
        int kcol = kk + h * 16;
        float s = s_part[0][qrow_p][kcol] + s_part[1][qrow_p][kcol]
                + s_part[2][qrow_p][kcol] + s_part[3][qrow_p][kcol];
        s *= 0.03125f;
        float p = (kv0 + kcol <= gq) ? __expf(s) : 0.f;
        u16 pb = f2bf(p);
        p_lds[qrow_p * 40 + kcol] = pb;
        psum += bf2f(pb);
      }
#pragma unroll
      for (int off = 1; off < 16; off <<= 1)
        psum += __shfl_xor(psum, off, 64);
      if (kk == 0) l_lds[qrow_p] += psum;
    }
#pragma unroll
    for (int i = 0; i < 8; ++i)
      *(uint4*)&kv_lds[(size_t)(i * 512 + tid) * 8] = rv[i];
    __syncthreads();
    bf16x8 pa0 = *(const bf16x8*)&p_lds[(0  + c16) * 40 + g * 8];
    bf16x8 pa1 = *(const bf16x8*)&p_lds[(16 + c16) * 40 + g * 8];
#pragma unroll
    for (int f = 0; f < 8; ++f) {
      int dcol = w * 128 + f * 16 + c16;
      int pos  = (dcol >> 4) * 64 + g * 16 + (dcol & 15);
      bf16x8 vf = *(const bf16x8*)&kv_lds[(size_t)pos * 8];
      oacc[0][f] = mfma16(pa0, vf, oacc[0][f]);
      oacc[1][f] = mfma16(pa1, vf, oacc[1][f]);
    }
  }

  float* Ob = Out + (size_t)b * 4096 * 1024;
#pragma unroll
  for (int qh = 0; qh < 2; ++qh) {
#pragma unroll
    for (int r = 0; r < 4; ++r) {
      int ql = qh * 16 + 4 * g + r;
      float linvv = 1.f / l_lds[ql];
#pragma unroll
      for (int f = 0; f < 8; ++f)
        Ob[(size_t)(qs + ql) * 1024 + w * 128 + f * 16 + c16] = oacc[qh][f][r] * linvv;
    }
  }
}

extern "C" void kernel_launch(void* const* d_in, const int* in_sizes, int n_in,
                              void* d_out, int out_size, void* d_ws, size_t ws_size,
                              hipStream_t stream) {
  const float* x  = (const float*)d_in[0];
  const float* Wq = (const float*)d_in[1];
  const float* Wk = (const float*)d_in[2];
  const float* Wv = (const float*)d_in[3];
  float* out = (float*)d_out;

  u16* ws    = (u16*)d_ws;
  u16* wWqkv = ws;                                   // 3M elems
  u16* wX    = wWqkv + (size_t)3 * 1024 * 1024;      // dead after qkv -> zero tile
  u16* wQ    = wX + (size_t)16384 * 1024;
  u16* wK    = wQ + (size_t)16384 * 1024;
  u16* wVT   = wK + (size_t)16384 * 1024;            // [4][1024][4096]
  u16* wSp   = wVT + (size_t)16384 * 1024;           // packed 128-tile triangle
  float* lpart = (float*)(ws + (size_t)104857600);   // 16384*16 f32 (1MB)

  cast_all<<<dim3(9728), 256, 0, stream>>>(x, Wq, Wk, Wv, wX, wWqkv);

  qkv_gemm<<<dim3(768), 512, 0, stream>>>(wX, wWqkv, wQ, wK, wVT);

  if (ws_size >= (size_t)211877888) {
    hipMemsetAsync(wX, 0, 32768, stream);            // zero tile for absent causal tiles
    sgemm_exp<<<dim3(136, 4), 512, 0, stream>>>(wQ, wK, wSp, lpart);
    pv_gemm<<<dim3(8, 8, 4), 512, 0, stream>>>(wSp, wVT, wX, lpart, out);
  } else {
    attn_kernel<<<dim3(512), 512, 0, stream>>>(wQ, wK, wVT, out);
  }
}